// Round 1
// 1331.722 us; speedup vs baseline: 1.3277x; 1.3277x over previous
//
#include <hip/hip_runtime.h>
#include <hip/hip_bf16.h>
#include <math.h>

#define D_MODEL 2048
#define D_FF    4096
#define NTOK    2048
#define NEXP    8
#define NPAIR   (NTOK*2)      // 4096 (token, expert) pairs, always exactly 2 per token
#define MAXTILES 48           // sum_e ceil(cnt_e/128) <= 4096/128 + 8 = 40

typedef __hip_bfloat16 bf16;
using frag_ab = __attribute__((ext_vector_type(8))) short;  // 8 bf16 (4 VGPRs)
using frag_cd = __attribute__((ext_vector_type(4))) float;  // 4 fp32 acc

__device__ __forceinline__ short f2bf_s(float f) {
  __hip_bfloat16 h = __float2bfloat16(f);
  union { __hip_bfloat16 b; short s; } u; u.b = h; return u.s;
}
__device__ __forceinline__ short4 f2bf4(const float4 v) {
  short4 r; r.x = f2bf_s(v.x); r.y = f2bf_s(v.y); r.z = f2bf_s(v.z); r.w = f2bf_s(v.w);
  return r;
}
__device__ __forceinline__ frag_ab pack8(const float4 v0, const float4 v1) {
  frag_ab r;
  r[0] = f2bf_s(v0.x); r[1] = f2bf_s(v0.y); r[2] = f2bf_s(v0.z); r[3] = f2bf_s(v0.w);
  r[4] = f2bf_s(v1.x); r[5] = f2bf_s(v1.y); r[6] = f2bf_s(v1.z); r[7] = f2bf_s(v1.w);
  return r;
}
// async 16B global -> LDS (linear dest = wave-uniform base + lane*16)
__device__ __forceinline__ void gload_lds16(const void* g, void* l) {
  __builtin_amdgcn_global_load_lds(
      (const __attribute__((address_space(1))) unsigned int*)g,
      (__attribute__((address_space(3))) unsigned int*)l, 16, 0, 0);
}

// ---------------- K0: zero control arrays (ws is poisoned 0xAA every launch) --------
__global__ void k_zero(int* cnt, int* cur, float* psum) {
  int t = threadIdx.x;
  if (t < NEXP) { cnt[t] = 0; cur[t] = 0; psum[t] = 0.f; }
}

// ---------------- K1: routing: logits -> softmax -> top2 -> normalized weights -----
__global__ void k_route(const float* __restrict__ x, const float* __restrict__ Wr,
                        int* __restrict__ tki, float* __restrict__ tkw,
                        int* __restrict__ cnt, float* __restrict__ psum) {
  const int n = blockIdx.x;
  const int t = threadIdx.x;
  const float* xr = x + (size_t)n * D_MODEL;
  float acc[NEXP];
#pragma unroll
  for (int e = 0; e < NEXP; e++) acc[e] = 0.f;
  for (int d = t; d < D_MODEL; d += 256) {
    float xv = xr[d];
#pragma unroll
    for (int e = 0; e < NEXP; e++) acc[e] += xv * Wr[e * D_MODEL + d];
  }
  __shared__ float red[256 * NEXP];
#pragma unroll
  for (int e = 0; e < NEXP; e++) red[t * NEXP + e] = acc[e];
  __syncthreads();
  __shared__ float logit[NEXP];
  if (t < NEXP) {
    float s = 0.f;
    for (int i = 0; i < 256; i++) s += red[i * NEXP + t];
    logit[t] = s;
  }
  __syncthreads();
  if (t == 0) {
    float m = logit[0];
#pragma unroll
    for (int e = 1; e < NEXP; e++) m = fmaxf(m, logit[e]);
    float p[NEXP]; float s = 0.f;
#pragma unroll
    for (int e = 0; e < NEXP; e++) { p[e] = expf(logit[e] - m); s += p[e]; }
    float inv = 1.f / s;
#pragma unroll
    for (int e = 0; e < NEXP; e++) p[e] *= inv;
    int i0 = 0;
#pragma unroll
    for (int e = 1; e < NEXP; e++) if (p[e] > p[i0]) i0 = e;
    int i1 = (i0 == 0) ? 1 : 0;
#pragma unroll
    for (int e = 0; e < NEXP; e++) if (e != i0 && e != i1 && p[e] > p[i1]) i1 = e;
    float wsum = p[i0] + p[i1];
    tki[n*2]   = i0;          tki[n*2+1] = i1;
    tkw[n*2]   = p[i0]/wsum;  tkw[n*2+1] = p[i1]/wsum;
    atomicAdd(&cnt[i0], 1);   atomicAdd(&cnt[i1], 1);
#pragma unroll
    for (int e = 0; e < NEXP; e++) atomicAdd(&psum[e], p[e]);
  }
}

// ---------------- K2: prefix scan, tile map, aux loss -------------------------------
__global__ void k_scan(const int* __restrict__ cnt, const float* __restrict__ psum,
                       int* __restrict__ off, int* __restrict__ te, int* __restrict__ tm,
                       float* __restrict__ aux_out) {
  if (threadIdx.x != 0) return;
  int o = 0;
  for (int e = 0; e < NEXP; e++) { off[e] = o; o += cnt[e]; }
  off[NEXP] = o;
  int nt = 0;
  for (int e = 0; e < NEXP; e++)
    for (int msv = 0; msv < cnt[e]; msv += 128) { te[nt] = e; tm[nt] = msv; nt++; }
  for (; nt < MAXTILES; nt++) { te[nt] = -1; tm[nt] = 0; }
  float aux = 0.f;
  for (int e = 0; e < NEXP; e++)
    aux += ((float)cnt[e] / (float)NPAIR) * (psum[e] / (float)NTOK);
  aux_out[0] = aux * 0.01f * (float)NEXP;
}

// ---------------- K3: assign ranks, build gather lists ------------------------------
__global__ void k_assign(const int* __restrict__ tki, const float* __restrict__ tkw,
                         const int* __restrict__ off, int* __restrict__ cur,
                         int* __restrict__ perm, float* __restrict__ pw,
                         int* __restrict__ posof) {
  int n = blockIdx.x * blockDim.x + threadIdx.x;
  if (n >= NTOK) return;
#pragma unroll
  for (int k = 0; k < 2; k++) {
    int e = tki[n*2+k];
    int r = atomicAdd(&cur[e], 1);
    int pos = off[e] + r;
    perm[pos] = n;
    pw[pos]   = tkw[n*2+k];
    posof[n*2+k] = pos;
  }
}

// ======================= FAST PATH (needs ~290 MiB workspace) =======================
// K-T: transpose+convert fp32 [E][K][F] -> bf16 [E][F][K], pre-swizzled:
// within each 64-k group (128 B), physical 16B chunk c holds logical k-octet (c ^ (f&7)).
// This makes linear global_load_lds staging in the GEMMs produce a bank-conflict-free
// swizzled LDS image (rule #21: inverse-swz source + swz on read).
template<int K, int F>
__global__ __launch_bounds__(256) void k_tpose(const float* __restrict__ src,
                                               bf16* __restrict__ dst) {
  const int e  = blockIdx.z;
  const int k0 = blockIdx.y * 128;
  const int f0 = blockIdx.x * 64;
  __shared__ float T[128][65];
  const int t = threadIdx.x;
  const float* s = src + (size_t)e * K * F;
  char* d = (char*)(dst + (size_t)e * F * K);
#pragma unroll
  for (int it = 0; it < 32; it++) {
    int kr = (t >> 6) + it * 4;
    T[kr][t & 63] = s[(size_t)(k0 + kr) * F + f0 + (t & 63)];
  }
  __syncthreads();
  const int fr  = t >> 2;
  const int key = fr & 7;          // (f0+fr)&7 == fr&7 since f0 % 64 == 0
  char* drow = d + (size_t)(f0 + fr) * K * 2 + (size_t)k0 * 2;
#pragma unroll
  for (int g = 0; g < 2; g++) {
#pragma unroll
    for (int cc = 0; cc < 2; cc++) {
      int c = (t & 3) * 2 + cc;    // physical chunk
      int l = c ^ key;             // logical k-octet stored there
      frag_ab r;
#pragma unroll
      for (int j = 0; j < 8; j++) r[j] = f2bf_s(T[g*64 + l*8 + j][fr]);
      *(frag_ab*)(drow + g*128 + c*16) = r;
    }
  }
}

// K4n: fused GEMM1: H = silu(X W1) * (X W3), bf16 MFMA, 128x128 tile, BK=64.
// B1/B3 staged via global_load_lds (16B) from pre-swizzled bf16 [f][k] weights.
// A gathered (perm) fp32->bf16, ds_write_b128 at swizzled chunk.
// ds_read_b128 with chunk XOR (row&7): 2-way max bank aliasing (free, m136).
__global__ __launch_bounds__(256, 2) void k_gemm1n(
    const float* __restrict__ x, const bf16* __restrict__ W1b,
    const bf16* __restrict__ W3b,
    const int* __restrict__ perm, const int* __restrict__ off,
    const int* __restrict__ tile_e, const int* __restrict__ tile_m,
    const int* __restrict__ cnt, bf16* __restrict__ H) {
  const int e = tile_e[blockIdx.y];
  if (e < 0) return;
  const int ms = tile_m[blockIdx.y];
  int mrows = cnt[e] - ms; if (mrows > 128) mrows = 128;
  const int f0 = blockIdx.x * 128;
  const int base = off[e] + ms;

  __shared__ __align__(16) bf16 As [128 * 64];
  __shared__ __align__(16) bf16 B1s[128 * 64];
  __shared__ __align__(16) bf16 B3s[128 * 64];
  __shared__ int permS[128];

  const int t = threadIdx.x;
  const int lane = t & 63;
  const int wuni = t & 192;          // wave-uniform base (4 waves)
  const int wid = t >> 6;
  const int wm = wid & 1, wn = wid >> 1;
  const int lm = lane & 15, q = lane >> 4;

  if (t < 128) permS[t] = (t < mrows) ? perm[base + t] : 0;

  frag_cd accg[4][4], accu[4][4];
#pragma unroll
  for (int i = 0; i < 4; i++)
#pragma unroll
    for (int j = 0; j < 4; j++) {
      accg[i][j] = {0.f,0.f,0.f,0.f};
      accu[i][j] = {0.f,0.f,0.f,0.f};
    }

  const char* W1e = (const char*)(W1b + (size_t)e * D_MODEL * D_FF);  // [f][k] bf16
  const char* W3e = (const char*)(W3b + (size_t)e * D_MODEL * D_FF);
  __syncthreads();

  for (int k0 = 0; k0 < D_MODEL; k0 += 64) {
    // B1/B3: 16 KB each, 1024 16B slots, linear LDS image (content pre-swizzled)
#pragma unroll
    for (int i = 0; i < 4; i++) {
      int wslot = i * 256 + wuni;
      int slot  = wslot + lane;
      int row = slot >> 3, c = slot & 7;
      size_t gb = (size_t)(f0 + row) * (D_MODEL * 2) + (size_t)k0 * 2 + c * 16;
      gload_lds16(W1e + gb, &B1s[wslot * 8]);
      gload_lds16(W3e + gb, &B3s[wslot * 8]);
    }
    // A: gather token rows, fp32 -> bf16, swizzled 16B LDS writes
#pragma unroll
    for (int i = 0; i < 4; i++) {
      int slot = i * 256 + t;        // 1024 slots = 128 rows x 8 octets
      int row = slot >> 3, c = slot & 7;
      int tok = permS[row];
      const float4* p = (const float4*)(x + (size_t)tok * D_MODEL + k0 + c * 8);
      frag_ab v = pack8(p[0], p[1]);
      *(frag_ab*)(&As[row * 64 + ((c ^ (row & 7)) * 8)]) = v;
    }
    __syncthreads();
#pragma unroll
    for (int ks = 0; ks < 2; ks++) {
      frag_ab a[4], b1[4], b3[4];
#pragma unroll
      for (int mf = 0; mf < 4; mf++) {
        int row = wm*64 + mf*16 + lm;
        int c = (ks*4 + q) ^ (row & 7);
        a[mf] = *(const frag_ab*)(&As[row * 64 + c * 8]);
      }
#pragma unroll
      for (int nf = 0; nf < 4; nf++) {
        int row = wn*64 + nf*16 + lm;
        int c = (ks*4 + q) ^ (row & 7);
        b1[nf] = *(const frag_ab*)(&B1s[row * 64 + c * 8]);
        b3[nf] = *(const frag_ab*)(&B3s[row * 64 + c * 8]);
      }
#pragma unroll
      for (int mf = 0; mf < 4; mf++)
#pragma unroll
        for (int nf = 0; nf < 4; nf++) {
          accg[mf][nf] = __builtin_amdgcn_mfma_f32_16x16x32_bf16(a[mf], b1[nf], accg[mf][nf], 0, 0, 0);
          accu[mf][nf] = __builtin_amdgcn_mfma_f32_16x16x32_bf16(a[mf], b3[nf], accu[mf][nf], 0, 0, 0);
        }
    }
    __syncthreads();
  }
  // epilogue: H = silu(g)*u, stored PRE-SWIZZLED bf16 so gemm2 can global_load_lds it.
  // swizzle key = row-within-tile & 7 (same tiling in gemm2 since ms % 128 == 0).
#pragma unroll
  for (int mf = 0; mf < 4; mf++) {
#pragma unroll
    for (int r = 0; r < 4; r++) {
      int row = wm*64 + mf*16 + q*4 + r;
      if (row < mrows) {
        char* hrow = (char*)H + (size_t)(base + row) * (D_FF * 2);
        int key = row & 7;
#pragma unroll
        for (int nf = 0; nf < 4; nf++) {
          float g = accg[mf][nf][r];
          float u = accu[mf][nf][r];
          float h = g * u / (1.f + expf(-g));   // silu(g)*u
          int f = f0 + wn*64 + nf*16 + lm;
          int grp = f >> 6, oct = (f >> 3) & 7, j = f & 7;
          *(bf16*)(hrow + grp*128 + ((oct ^ key) * 16) + j*2) = __float2bfloat16(h);
        }
      }
    }
  }
}

// K5n: GEMM2: eo = w * (H W2), 128x128 tile, BK=64, both operands via global_load_lds.
__global__ __launch_bounds__(256, 3) void k_gemm2n(
    const bf16* __restrict__ H, const bf16* __restrict__ W2b,
    const float* __restrict__ pw,
    const int* __restrict__ off, const int* __restrict__ tile_e,
    const int* __restrict__ tile_m, const int* __restrict__ cnt,
    float* __restrict__ eo) {
  const int e = tile_e[blockIdx.y];
  if (e < 0) return;
  const int ms = tile_m[blockIdx.y];
  int mrows = cnt[e] - ms; if (mrows > 128) mrows = 128;
  const int d0 = blockIdx.x * 128;
  const int base = off[e] + ms;

  __shared__ __align__(16) bf16 As[128 * 64];
  __shared__ __align__(16) bf16 Bs[128 * 64];

  const int t = threadIdx.x;
  const int lane = t & 63;
  const int wuni = t & 192;
  const int wid = t >> 6;
  const int wm = wid & 1, wn = wid >> 1;
  const int lm = lane & 15, q = lane >> 4;

  frag_cd acc[4][4];
#pragma unroll
  for (int i = 0; i < 4; i++)
#pragma unroll
    for (int j = 0; j < 4; j++) acc[i][j] = {0.f,0.f,0.f,0.f};

  const char* W2e = (const char*)(W2b + (size_t)e * D_FF * D_MODEL);  // [d][f] bf16
  const char* Hb  = (const char*)H;

  for (int k0 = 0; k0 < D_FF; k0 += 64) {
#pragma unroll
    for (int i = 0; i < 4; i++) {
      int wslot = i * 256 + wuni;
      int slot  = wslot + lane;
      int row = slot >> 3, c = slot & 7;
      // A: H rows (pre-swizzled bf16). Rows >= mrows read in-bounds garbage, discarded.
      gload_lds16(Hb + (size_t)(base + row) * (D_FF * 2) + (size_t)k0 * 2 + c * 16,
                  &As[wslot * 8]);
      gload_lds16(W2e + (size_t)(d0 + row) * (D_FF * 2) + (size_t)k0 * 2 + c * 16,
                  &Bs[wslot * 8]);
    }
    __syncthreads();
#pragma unroll
    for (int ks = 0; ks < 2; ks++) {
      frag_ab a[4], b[4];
#pragma unroll
      for (int mf = 0; mf < 4; mf++) {
        int row = wm*64 + mf*16 + lm;
        int c = (ks*4 + q) ^ (row & 7);
        a[mf] = *(const frag_ab*)(&As[row * 64 + c * 8]);
      }
#pragma unroll
      for (int nf = 0; nf < 4; nf++) {
        int row = wn*64 + nf*16 + lm;
        int c = (ks*4 + q) ^ (row & 7);
        b[nf] = *(const frag_ab*)(&Bs[row * 64 + c * 8]);
      }
#pragma unroll
      for (int mf = 0; mf < 4; mf++)
#pragma unroll
        for (int nf = 0; nf < 4; nf++)
          acc[mf][nf] = __builtin_amdgcn_mfma_f32_16x16x32_bf16(a[mf], b[nf], acc[mf][nf], 0, 0, 0);
    }
    __syncthreads();
  }
#pragma unroll
  for (int mf = 0; mf < 4; mf++) {
#pragma unroll
    for (int r = 0; r < 4; r++) {
      int row = wm*64 + mf*16 + q*4 + r;
      if (row < mrows) {
        float w = pw[base + row];
        float* orow = eo + (size_t)(base + row) * D_MODEL;
#pragma unroll
        for (int nf = 0; nf < 4; nf++)
          orow[d0 + wn*64 + nf*16 + lm] = w * acc[mf][nf][r];
      }
    }
  }
}

// ======================= FALLBACK PATH (original kernels) ===========================
__global__ __launch_bounds__(256) void k_gemm1(
    const float* __restrict__ x, const float* __restrict__ W1,
    const float* __restrict__ W3,
    const int* __restrict__ perm, const int* __restrict__ off,
    const int* __restrict__ tile_e, const int* __restrict__ tile_m,
    const int* __restrict__ cnt, bf16* __restrict__ H) {
  const int e = tile_e[blockIdx.y];
  if (e < 0) return;
  const int ms = tile_m[blockIdx.y];
  int mrows = cnt[e] - ms; if (mrows > 128) mrows = 128;
  const int f0 = blockIdx.x * 128;
  const int base = off[e] + ms;

  __shared__ __align__(16) bf16 As [128 * 40];
  __shared__ __align__(16) bf16 B1s[128 * 40];
  __shared__ __align__(16) bf16 B3s[128 * 40];
  __shared__ int permS[128];

  const int t = threadIdx.x;
  const int lane = t & 63, wid = t >> 6;
  const int wm = wid & 1, wn = wid >> 1;
  const int lm = lane & 15, q = lane >> 4;

  if (t < 128) permS[t] = (t < mrows) ? perm[base + t] : 0;

  frag_cd accg[4][4], accu[4][4];
#pragma unroll
  for (int i = 0; i < 4; i++)
#pragma unroll
    for (int j = 0; j < 4; j++) {
      accg[i][j] = {0.f,0.f,0.f,0.f};
      accu[i][j] = {0.f,0.f,0.f,0.f};
    }

  const float* W1e = W1 + (size_t)e * D_MODEL * D_FF;
  const float* W3e = W3 + (size_t)e * D_MODEL * D_FF;
  __syncthreads();

  for (int k0 = 0; k0 < D_MODEL; k0 += 32) {
#pragma unroll
    for (int i = 0; i < 4; i++) {
      int s = t + i * 256;
      int row = s >> 3, kg = s & 7;
      float4 v = make_float4(0.f, 0.f, 0.f, 0.f);
      if (row < mrows) {
        int tok = permS[row];
        v = *(const float4*)(x + (size_t)tok * D_MODEL + k0 + kg * 4);
      }
      *(short4*)(&As[row * 40 + kg * 4]) = f2bf4(v);
    }
#pragma unroll
    for (int i = 0; i < 2; i++) {
      int s = t + i * 256;
      int f = s & 127, kg = s >> 7;
      const float* g1 = W1e + (size_t)(k0 + kg * 8) * D_FF + f0 + f;
      const float* g3 = W3e + (size_t)(k0 + kg * 8) * D_FF + f0 + f;
      short r1[8], r3[8];
#pragma unroll
      for (int j = 0; j < 8; j++) r1[j] = f2bf_s(g1[(size_t)j * D_FF]);
#pragma unroll
      for (int j = 0; j < 8; j++) r3[j] = f2bf_s(g3[(size_t)j * D_FF]);
      *(frag_ab*)(&B1s[f * 40 + kg * 8]) = *(const frag_ab*)r1;
      *(frag_ab*)(&B3s[f * 40 + kg * 8]) = *(const frag_ab*)r3;
    }
    __syncthreads();
    frag_ab a[4], b1[4], b3[4];
#pragma unroll
    for (int mf = 0; mf < 4; mf++)
      a[mf] = *(const frag_ab*)(&As[(wm*64 + mf*16 + lm) * 40 + q*8]);
#pragma unroll
    for (int nf = 0; nf < 4; nf++) {
      b1[nf] = *(const frag_ab*)(&B1s[(wn*64 + nf*16 + lm) * 40 + q*8]);
      b3[nf] = *(const frag_ab*)(&B3s[(wn*64 + nf*16 + lm) * 40 + q*8]);
    }
#pragma unroll
    for (int mf = 0; mf < 4; mf++)
#pragma unroll
      for (int nf = 0; nf < 4; nf++) {
        accg[mf][nf] = __builtin_amdgcn_mfma_f32_16x16x32_bf16(a[mf], b1[nf], accg[mf][nf], 0, 0, 0);
        accu[mf][nf] = __builtin_amdgcn_mfma_f32_16x16x32_bf16(a[mf], b3[nf], accu[mf][nf], 0, 0, 0);
      }
    __syncthreads();
  }
#pragma unroll
  for (int mf = 0; mf < 4; mf++) {
#pragma unroll
    for (int r = 0; r < 4; r++) {
      int row = wm*64 + mf*16 + q*4 + r;
      if (row < mrows) {
        bf16* hrow = H + (size_t)(base + row) * D_FF;
#pragma unroll
        for (int nf = 0; nf < 4; nf++) {
          float g = accg[mf][nf][r];
          float u = accu[mf][nf][r];
          float h = g * u / (1.f + expf(-g));
          hrow[f0 + wn*64 + nf*16 + lm] = __float2bfloat16(h);
        }
      }
    }
  }
}

__global__ __launch_bounds__(256) void k_gemm2(
    const bf16* __restrict__ H, const float* __restrict__ W2,
    const float* __restrict__ pw,
    const int* __restrict__ off, const int* __restrict__ tile_e,
    const int* __restrict__ tile_m, const int* __restrict__ cnt,
    float* __restrict__ eo) {
  const int e = tile_e[blockIdx.y];
  if (e < 0) return;
  const int ms = tile_m[blockIdx.y];
  int mrows = cnt[e] - ms; if (mrows > 128) mrows = 128;
  const int d0 = blockIdx.x * 128;
  const int base = off[e] + ms;

  __shared__ __align__(16) bf16 As[128 * 40];
  __shared__ __align__(16) bf16 Bs[128 * 40];

  const int t = threadIdx.x;
  const int lane = t & 63, wid = t >> 6;
  const int wm = wid & 1, wn = wid >> 1;
  const int lm = lane & 15, q = lane >> 4;

  frag_cd acc[4][4];
#pragma unroll
  for (int i = 0; i < 4; i++)
#pragma unroll
    for (int j = 0; j < 4; j++) acc[i][j] = {0.f,0.f,0.f,0.f};

  const float* W2e = W2 + (size_t)e * D_FF * D_MODEL;
  const short* Hs = (const short*)H;

  for (int k0 = 0; k0 < D_FF; k0 += 32) {
#pragma unroll
    for (int i = 0; i < 2; i++) {
      int s = t + i * 256;
      int row = s >> 2, kg = s & 3;
      frag_ab v = {0,0,0,0,0,0,0,0};
      if (row < mrows)
        v = *(const frag_ab*)(Hs + (size_t)(base + row) * D_FF + k0 + kg * 8);
      *(frag_ab*)(&As[row * 40 + kg * 8]) = v;
    }
#pragma unroll
    for (int i = 0; i < 2; i++) {
      int s = t + i * 256;
      int dd = s & 127, kg = s >> 7;
      const float* g2 = W2e + (size_t)(k0 + kg * 8) * D_MODEL + d0 + dd;
      short r2[8];
#pragma unroll
      for (int j = 0; j < 8; j++) r2[j] = f2bf_s(g2[(size_t)j * D_MODEL]);
      *(frag_ab*)(&Bs[dd * 40 + kg * 8]) = *(const frag_ab*)r2;
    }
    __syncthreads();
    frag_ab a[4], b[4];
#pragma unroll
    for (int mf = 0; mf < 4; mf++)
      a[mf] = *(const frag_ab*)(&As[(wm*64 + mf*16 + lm) * 40 + q*8]);
#pragma unroll
    for (int nf = 0; nf < 4; nf++)
      b[nf] = *(const frag_ab*)(&Bs[(wn*64 + nf*16 + lm) * 40 + q*8]);
#pragma unroll
    for (int mf = 0; mf < 4; mf++)
#pragma unroll
      for (int nf = 0; nf < 4; nf++)
        acc[mf][nf] = __builtin_amdgcn_mfma_f32_16x16x32_bf16(a[mf], b[nf], acc[mf][nf], 0, 0, 0);
    __syncthreads();
  }
#pragma unroll
  for (int mf = 0; mf < 4; mf++) {
#pragma unroll
    for (int r = 0; r < 4; r++) {
      int row = wm*64 + mf*16 + q*4 + r;
      if (row < mrows) {
        float w = pw[base + row];
        float* orow = eo + (size_t)(base + row) * D_MODEL;
#pragma unroll
        for (int nf = 0; nf < 4; nf++)
          orow[d0 + wn*64 + nf*16 + lm] = w * acc[mf][nf][r];
      }
    }
  }
}

// ---------------- K6: combine the two expert outputs per token ----------------------
__global__ void k_combine(const float* __restrict__ eo, const int* __restrict__ posof,
                          float* __restrict__ out) {
  int idx = blockIdx.x * 256 + threadIdx.x;
  int n = idx >> 9;
  int c = (idx & 511) * 4;
  int p0 = posof[n*2], p1 = posof[n*2+1];
  const float4 a = *(const float4*)(eo + (size_t)p0 * D_MODEL + c);
  const float4 b = *(const float4*)(eo + (size_t)p1 * D_MODEL + c);
  float4 r;
  r.x = a.x + b.x; r.y = a.y + b.y; r.z = a.z + b.z; r.w = a.w + b.w;
  *(float4*)(out + (size_t)n * D_MODEL + c) = r;
}

extern "C" void kernel_launch(void* const* d_in, const int* in_sizes, int n_in,
                              void* d_out, int out_size, void* d_ws, size_t ws_size,
                              hipStream_t stream) {
  const float* x  = (const float*)d_in[0];
  const float* Wr = (const float*)d_in[1];
  const float* W1 = (const float*)d_in[2];
  const float* W3 = (const float*)d_in[3];
  const float* W2 = (const float*)d_in[4];
  float* out = (float*)d_out;
  char* ws = (char*)d_ws;

  // fast path needs: W1b(128MiB)+W3b(128MiB)+H(32MiB)+ctrl; W2b/eo alias W1b/W3b
  // after gemm1. +1MiB slack covers gemm2's guarded-but-issued A reads past H end.
  const size_t REQ = (290ull << 20);
  if (ws_size >= REQ) {
    bf16*  W1b = (bf16*)(ws);
    bf16*  W3b = (bf16*)(ws + (128ull << 20));
    bf16*  Hb  = (bf16*)(ws + (256ull << 20));
    bf16*  W2b = (bf16*)(ws);                    // alias: W1b dead after gemm1
    float* eo  = (float*)(ws + (128ull << 20));  // alias: W3b dead after gemm1
    char*  ib  = ws + (289ull << 20);
    int*   perm  = (int*)(ib);
    float* pw    = (float*)(ib + 16384);
    int*   posof = (int*)(ib + 32768);
    int*   tki   = (int*)(ib + 49152);
    float* tkw   = (float*)(ib + 65536);
    int*   cnt   = (int*)(ib + 81920);
    int*   cur   = (int*)(ib + 82048);
    int*   off   = (int*)(ib + 82176);
    int*   te    = (int*)(ib + 82432);
    int*   tm    = (int*)(ib + 82688);
    float* psum  = (float*)(ib + 82944);

    k_zero<<<1, 64, 0, stream>>>(cnt, cur, psum);
    k_route<<<NTOK, 256, 0, stream>>>(x, Wr, tki, tkw, cnt, psum);
    k_scan<<<1, 1, 0, stream>>>(cnt, psum, off, te, tm, out + (size_t)NTOK * D_MODEL);
    k_assign<<<NTOK/256, 256, 0, stream>>>(tki, tkw, off, cur, perm, pw, posof);
    k_tpose<D_MODEL, D_FF><<<dim3(D_FF/64, D_MODEL/128, NEXP), 256, 0, stream>>>(W1, W1b);
    k_tpose<D_MODEL, D_FF><<<dim3(D_FF/64, D_MODEL/128, NEXP), 256, 0, stream>>>(W3, W3b);
    k_gemm1n<<<dim3(D_FF/128, MAXTILES), 256, 0, stream>>>(x, W1b, W3b, perm, off, te, tm, cnt, Hb);
    k_tpose<D_FF, D_MODEL><<<dim3(D_MODEL/64, D_FF/128, NEXP), 256, 0, stream>>>(W2, W2b);
    k_gemm2n<<<dim3(D_MODEL/128, MAXTILES), 256, 0, stream>>>(Hb, W2b, pw, off, te, tm, cnt, eo);
    k_combine<<<(NTOK*(D_MODEL/4))/256, 256, 0, stream>>>(eo, posof, out);
  } else {
    // -------- fallback: original 67 MiB layout + original kernels --------
    bf16*  H    = (bf16*)(ws);
    float* eo   = (float*)(ws + 33554432);
    char*  ib   = ws + 67108864;
    int*   perm  = (int*)(ib);
    float* pw    = (float*)(ib + 16384);
    int*   posof = (int*)(ib + 32768);
    int*   tki   = (int*)(ib + 49152);
    float* tkw   = (float*)(ib + 65536);
    int*   cnt   = (int*)(ib + 81920);
    int*   cur   = (int*)(ib + 82048);
    int*   off   = (int*)(ib + 82176);
    int*   te    = (int*)(ib + 82432);
    int*   tm    = (int*)(ib + 82688);
    float* psum  = (float*)(ib + 82944);

    k_zero<<<1, 64, 0, stream>>>(cnt, cur, psum);
    k_route<<<NTOK, 256, 0, stream>>>(x, Wr, tki, tkw, cnt, psum);
    k_scan<<<1, 1, 0, stream>>>(cnt, psum, off, te, tm, out + (size_t)NTOK * D_MODEL);
    k_assign<<<NTOK/256, 256, 0, stream>>>(tki, tkw, off, cur, perm, pw, posof);
    k_gemm1<<<dim3(D_FF/128, MAXTILES), 256, 0, stream>>>(x, W1, W3, perm, off, te, tm, cnt, H);
    k_gemm2<<<dim3(D_MODEL/128, MAXTILES), 256, 0, stream>>>(H, W2, pw, off, te, tm, cnt, eo);
    k_combine<<<(NTOK*(D_MODEL/4))/256, 256, 0, stream>>>(eo, posof, out);
  }
}

// Round 2
// 1327.596 us; speedup vs baseline: 1.3318x; 1.0031x over previous
//
#include <hip/hip_runtime.h>
#include <hip/hip_bf16.h>
#include <math.h>

#define D_MODEL 2048
#define D_FF    4096
#define NTOK    2048
#define NEXP    8
#define NPAIR   (NTOK*2)      // 4096 (token, expert) pairs, always exactly 2 per token
#define MAXTILES 48           // sum_e ceil(cnt_e/128) <= 4096/128 + 8 = 40

typedef __hip_bfloat16 bf16;
using frag_ab = __attribute__((ext_vector_type(8))) short;  // 8 bf16 (4 VGPRs)
using frag_cd = __attribute__((ext_vector_type(4))) float;  // 4 fp32 acc

__device__ __forceinline__ short f2bf_s(float f) {
  __hip_bfloat16 h = __float2bfloat16(f);
  union { __hip_bfloat16 b; short s; } u; u.b = h; return u.s;
}
__device__ __forceinline__ short4 f2bf4(const float4 v) {
  short4 r; r.x = f2bf_s(v.x); r.y = f2bf_s(v.y); r.z = f2bf_s(v.z); r.w = f2bf_s(v.w);
  return r;
}
__device__ __forceinline__ frag_ab pack8(const float4 v0, const float4 v1) {
  frag_ab r;
  r[0] = f2bf_s(v0.x); r[1] = f2bf_s(v0.y); r[2] = f2bf_s(v0.z); r[3] = f2bf_s(v0.w);
  r[4] = f2bf_s(v1.x); r[5] = f2bf_s(v1.y); r[6] = f2bf_s(v1.z); r[7] = f2bf_s(v1.w);
  return r;
}
// async 16B global -> LDS (linear dest = wave-uniform base + lane*16)
__device__ __forceinline__ void gload_lds16(const void* g, void* l) {
  __builtin_amdgcn_global_load_lds(
      (const __attribute__((address_space(1))) unsigned int*)g,
      (__attribute__((address_space(3))) unsigned int*)l, 16, 0, 0);
}

// ---------------- K0: zero control arrays (ws is poisoned 0xAA every launch) --------
__global__ void k_zero(int* cnt, int* cur, float* psum) {
  int t = threadIdx.x;
  if (t < NEXP) { cnt[t] = 0; cur[t] = 0; psum[t] = 0.f; }
}

// ---------------- K1: routing: logits -> softmax -> top2 -> normalized weights -----
__global__ void k_route(const float* __restrict__ x, const float* __restrict__ Wr,
                        int* __restrict__ tki, float* __restrict__ tkw,
                        int* __restrict__ cnt, float* __restrict__ psum) {
  const int n = blockIdx.x;
  const int t = threadIdx.x;
  const float* xr = x + (size_t)n * D_MODEL;
  float acc[NEXP];
#pragma unroll
  for (int e = 0; e < NEXP; e++) acc[e] = 0.f;
  for (int d = t; d < D_MODEL; d += 256) {
    float xv = xr[d];
#pragma unroll
    for (int e = 0; e < NEXP; e++) acc[e] += xv * Wr[e * D_MODEL + d];
  }
  __shared__ float red[256 * NEXP];
#pragma unroll
  for (int e = 0; e < NEXP; e++) red[t * NEXP + e] = acc[e];
  __syncthreads();
  __shared__ float logit[NEXP];
  if (t < NEXP) {
    float s = 0.f;
    for (int i = 0; i < 256; i++) s += red[i * NEXP + t];
    logit[t] = s;
  }
  __syncthreads();
  if (t == 0) {
    float m = logit[0];
#pragma unroll
    for (int e = 1; e < NEXP; e++) m = fmaxf(m, logit[e]);
    float p[NEXP]; float s = 0.f;
#pragma unroll
    for (int e = 0; e < NEXP; e++) { p[e] = expf(logit[e] - m); s += p[e]; }
    float inv = 1.f / s;
#pragma unroll
    for (int e = 0; e < NEXP; e++) p[e] *= inv;
    int i0 = 0;
#pragma unroll
    for (int e = 1; e < NEXP; e++) if (p[e] > p[i0]) i0 = e;
    int i1 = (i0 == 0) ? 1 : 0;
#pragma unroll
    for (int e = 0; e < NEXP; e++) if (e != i0 && e != i1 && p[e] > p[i1]) i1 = e;
    float wsum = p[i0] + p[i1];
    tki[n*2]   = i0;          tki[n*2+1] = i1;
    tkw[n*2]   = p[i0]/wsum;  tkw[n*2+1] = p[i1]/wsum;
    atomicAdd(&cnt[i0], 1);   atomicAdd(&cnt[i1], 1);
#pragma unroll
    for (int e = 0; e < NEXP; e++) atomicAdd(&psum[e], p[e]);
  }
}

// ---------------- K2: prefix scan, tile map, aux loss -------------------------------
__global__ void k_scan(const int* __restrict__ cnt, const float* __restrict__ psum,
                       int* __restrict__ off, int* __restrict__ te, int* __restrict__ tm,
                       float* __restrict__ aux_out) {
  if (threadIdx.x != 0) return;
  int o = 0;
  for (int e = 0; e < NEXP; e++) { off[e] = o; o += cnt[e]; }
  off[NEXP] = o;
  int nt = 0;
  for (int e = 0; e < NEXP; e++)
    for (int msv = 0; msv < cnt[e]; msv += 128) { te[nt] = e; tm[nt] = msv; nt++; }
  for (; nt < MAXTILES; nt++) { te[nt] = -1; tm[nt] = 0; }
  float aux = 0.f;
  for (int e = 0; e < NEXP; e++)
    aux += ((float)cnt[e] / (float)NPAIR) * (psum[e] / (float)NTOK);
  aux_out[0] = aux * 0.01f * (float)NEXP;
}

// ---------------- K3: assign ranks, build gather lists ------------------------------
__global__ void k_assign(const int* __restrict__ tki, const float* __restrict__ tkw,
                         const int* __restrict__ off, int* __restrict__ cur,
                         int* __restrict__ perm, float* __restrict__ pw,
                         int* __restrict__ posof) {
  int n = blockIdx.x * blockDim.x + threadIdx.x;
  if (n >= NTOK) return;
#pragma unroll
  for (int k = 0; k < 2; k++) {
    int e = tki[n*2+k];
    int r = atomicAdd(&cur[e], 1);
    int pos = off[e] + r;
    perm[pos] = n;
    pw[pos]   = tkw[n*2+k];
    posof[n*2+k] = pos;
  }
}

// ======================= FAST PATH (needs ~290 MiB workspace) =======================
// K-T: transpose+convert fp32 [E][K][F] -> bf16 [E][F][K], pre-swizzled:
// within each 64-k group (128 B), physical 16B chunk c holds logical k-octet (c ^ (f&7)).
// Rewritten R1: float4 global reads (256B/16-lane group), contiguous 256B row-segment
// writes (16 consecutive lanes cover 8 chunks of one row), LDS quad-XOR swizzle
// (quad' = quad ^ ((row>>3)&7)): keeps 16B-aligned ds_write_b128 AND gives 2-way (free)
// bank aliasing on the column reads.
template<int K, int F>
__device__ __forceinline__ void tpose_body(const float* __restrict__ s,
                                           char* __restrict__ d,
                                           int k0, int f0, int t, float* T /*[128*64]*/) {
  // phase 1: load [128k][64f] fp32 tile, swizzled float4 LDS writes
#pragma unroll
  for (int i = 0; i < 8; i++) {
    int sl = t + i * 256;              // 2048 slots = 128 rows x 16 quads
    int kr = sl >> 4, q4 = sl & 15;
    float4 v = *(const float4*)(s + (size_t)(k0 + kr) * F + f0 + q4 * 4);
    int qs = q4 ^ ((kr >> 3) & 7);
    *(float4*)(&T[kr * 64 + qs * 4]) = v;
  }
  __syncthreads();
  // phase 2: emit [64f][128k] bf16, chunk c of group g holds octet l = c ^ (f&7)
#pragma unroll
  for (int i = 0; i < 4; i++) {
    int sl = t + i * 256;              // 1024 slots = 64 rows x 2 groups x 8 chunks
    int fr = sl >> 4, cg = sl & 15;
    int g = cg >> 3, c = cg & 7;
    int l = c ^ (fr & 7);
    int rbase = g * 64 + l * 8;        // (rbase>>3)&7 == l  (j<8 doesn't carry)
    int col = (fr & 3) + (((fr >> 2) ^ l) << 2);
    frag_ab r;
#pragma unroll
    for (int j = 0; j < 8; j++) r[j] = f2bf_s(T[(rbase + j) * 64 + col]);
    *(frag_ab*)(d + (size_t)(f0 + fr) * K * 2 + (size_t)k0 * 2 + g * 128 + c * 16) = r;
  }
}

template<int K, int F>
__global__ __launch_bounds__(256) void k_tpose(const float* __restrict__ src,
                                               bf16* __restrict__ dst) {
  __shared__ __align__(16) float T[128 * 64];
  const int e = blockIdx.z;
  tpose_body<K, F>(src + (size_t)e * K * F, (char*)(dst + (size_t)e * F * K),
                   blockIdx.y * 128, blockIdx.x * 64, threadIdx.x, T);
}

template<int K, int F>
__global__ __launch_bounds__(256) void k_tpose_dual(const float* __restrict__ srcA,
                                                    const float* __restrict__ srcB,
                                                    bf16* __restrict__ dstA,
                                                    bf16* __restrict__ dstB) {
  __shared__ __align__(16) float T[128 * 64];
  const int e = blockIdx.z & 7;
  const float* src = (blockIdx.z & 8) ? srcB : srcA;
  bf16*        dst = (blockIdx.z & 8) ? dstB : dstA;
  tpose_body<K, F>(src + (size_t)e * K * F, (char*)(dst + (size_t)e * F * K),
                   blockIdx.y * 128, blockIdx.x * 64, threadIdx.x, T);
}

// K4n: fused GEMM1: H = silu(X W1) * (X W3), bf16 MFMA, 128x128 tile, BK=64.
// B1/B3 staged via global_load_lds (16B) from pre-swizzled bf16 [f][k] weights.
// A gathered (perm) fp32->bf16, ds_write_b128 at swizzled chunk.
// ds_read_b128 with chunk XOR (row&7): 2-way max bank aliasing (free, m136).
__global__ __launch_bounds__(256, 2) void k_gemm1n(
    const float* __restrict__ x, const bf16* __restrict__ W1b,
    const bf16* __restrict__ W3b,
    const int* __restrict__ perm, const int* __restrict__ off,
    const int* __restrict__ tile_e, const int* __restrict__ tile_m,
    const int* __restrict__ cnt, bf16* __restrict__ H) {
  const int e = tile_e[blockIdx.y];
  if (e < 0) return;
  const int ms = tile_m[blockIdx.y];
  int mrows = cnt[e] - ms; if (mrows > 128) mrows = 128;
  const int f0 = blockIdx.x * 128;
  const int base = off[e] + ms;

  __shared__ __align__(16) bf16 As [128 * 64];
  __shared__ __align__(16) bf16 B1s[128 * 64];
  __shared__ __align__(16) bf16 B3s[128 * 64];
  __shared__ int permS[128];

  const int t = threadIdx.x;
  const int lane = t & 63;
  const int wuni = t & 192;          // wave-uniform base (4 waves)
  const int wid = t >> 6;
  const int wm = wid & 1, wn = wid >> 1;
  const int lm = lane & 15, q = lane >> 4;

  if (t < 128) permS[t] = (t < mrows) ? perm[base + t] : 0;

  frag_cd accg[4][4], accu[4][4];
#pragma unroll
  for (int i = 0; i < 4; i++)
#pragma unroll
    for (int j = 0; j < 4; j++) {
      accg[i][j] = {0.f,0.f,0.f,0.f};
      accu[i][j] = {0.f,0.f,0.f,0.f};
    }

  const char* W1e = (const char*)(W1b + (size_t)e * D_MODEL * D_FF);  // [f][k] bf16
  const char* W3e = (const char*)(W3b + (size_t)e * D_MODEL * D_FF);
  __syncthreads();

  for (int k0 = 0; k0 < D_MODEL; k0 += 64) {
    // B1/B3: 16 KB each, 1024 16B slots, linear LDS image (content pre-swizzled)
#pragma unroll
    for (int i = 0; i < 4; i++) {
      int wslot = i * 256 + wuni;
      int slot  = wslot + lane;
      int row = slot >> 3, c = slot & 7;
      size_t gb = (size_t)(f0 + row) * (D_MODEL * 2) + (size_t)k0 * 2 + c * 16;
      gload_lds16(W1e + gb, &B1s[wslot * 8]);
      gload_lds16(W3e + gb, &B3s[wslot * 8]);
    }
    // A: gather token rows, fp32 -> bf16, swizzled 16B LDS writes
#pragma unroll
    for (int i = 0; i < 4; i++) {
      int slot = i * 256 + t;        // 1024 slots = 128 rows x 8 octets
      int row = slot >> 3, c = slot & 7;
      int tok = permS[row];
      const float4* p = (const float4*)(x + (size_t)tok * D_MODEL + k0 + c * 8);
      frag_ab v = pack8(p[0], p[1]);
      *(frag_ab*)(&As[row * 64 + ((c ^ (row & 7)) * 8)]) = v;
    }
    __syncthreads();
#pragma unroll
    for (int ks = 0; ks < 2; ks++) {
      frag_ab a[4], b1[4], b3[4];
#pragma unroll
      for (int mf = 0; mf < 4; mf++) {
        int row = wm*64 + mf*16 + lm;
        int c = (ks*4 + q) ^ (row & 7);
        a[mf] = *(const frag_ab*)(&As[row * 64 + c * 8]);
      }
#pragma unroll
      for (int nf = 0; nf < 4; nf++) {
        int row = wn*64 + nf*16 + lm;
        int c = (ks*4 + q) ^ (row & 7);
        b1[nf] = *(const frag_ab*)(&B1s[row * 64 + c * 8]);
        b3[nf] = *(const frag_ab*)(&B3s[row * 64 + c * 8]);
      }
#pragma unroll
      for (int mf = 0; mf < 4; mf++)
#pragma unroll
        for (int nf = 0; nf < 4; nf++) {
          accg[mf][nf] = __builtin_amdgcn_mfma_f32_16x16x32_bf16(a[mf], b1[nf], accg[mf][nf], 0, 0, 0);
          accu[mf][nf] = __builtin_amdgcn_mfma_f32_16x16x32_bf16(a[mf], b3[nf], accu[mf][nf], 0, 0, 0);
        }
    }
    __syncthreads();
  }
  // epilogue: H = silu(g)*u, stored PRE-SWIZZLED bf16 so gemm2 can global_load_lds it.
  // swizzle key = row-within-tile & 7 (same tiling in gemm2 since ms % 128 == 0).
#pragma unroll
  for (int mf = 0; mf < 4; mf++) {
#pragma unroll
    for (int r = 0; r < 4; r++) {
      int row = wm*64 + mf*16 + q*4 + r;
      if (row < mrows) {
        char* hrow = (char*)H + (size_t)(base + row) * (D_FF * 2);
        int key = row & 7;
#pragma unroll
        for (int nf = 0; nf < 4; nf++) {
          float g = accg[mf][nf][r];
          float u = accu[mf][nf][r];
          float h = g * u / (1.f + expf(-g));   // silu(g)*u
          int f = f0 + wn*64 + nf*16 + lm;
          int grp = f >> 6, oct = (f >> 3) & 7, j = f & 7;
          *(bf16*)(hrow + grp*128 + ((oct ^ key) * 16) + j*2) = __float2bfloat16(h);
        }
      }
    }
  }
}

// K5n: GEMM2: eo = w * (H W2), 128x128 tile, BK=64, both operands via global_load_lds.
__global__ __launch_bounds__(256, 3) void k_gemm2n(
    const bf16* __restrict__ H, const bf16* __restrict__ W2b,
    const float* __restrict__ pw,
    const int* __restrict__ off, const int* __restrict__ tile_e,
    const int* __restrict__ tile_m, const int* __restrict__ cnt,
    float* __restrict__ eo) {
  const int e = tile_e[blockIdx.y];
  if (e < 0) return;
  const int ms = tile_m[blockIdx.y];
  int mrows = cnt[e] - ms; if (mrows > 128) mrows = 128;
  const int d0 = blockIdx.x * 128;
  const int base = off[e] + ms;

  __shared__ __align__(16) bf16 As[128 * 64];
  __shared__ __align__(16) bf16 Bs[128 * 64];

  const int t = threadIdx.x;
  const int lane = t & 63;
  const int wuni = t & 192;
  const int wid = t >> 6;
  const int wm = wid & 1, wn = wid >> 1;
  const int lm = lane & 15, q = lane >> 4;

  frag_cd acc[4][4];
#pragma unroll
  for (int i = 0; i < 4; i++)
#pragma unroll
    for (int j = 0; j < 4; j++) acc[i][j] = {0.f,0.f,0.f,0.f};

  const char* W2e = (const char*)(W2b + (size_t)e * D_FF * D_MODEL);  // [d][f] bf16
  const char* Hb  = (const char*)H;

  for (int k0 = 0; k0 < D_FF; k0 += 64) {
#pragma unroll
    for (int i = 0; i < 4; i++) {
      int wslot = i * 256 + wuni;
      int slot  = wslot + lane;
      int row = slot >> 3, c = slot & 7;
      // A: H rows (pre-swizzled bf16). Rows >= mrows read in-bounds garbage, discarded.
      gload_lds16(Hb + (size_t)(base + row) * (D_FF * 2) + (size_t)k0 * 2 + c * 16,
                  &As[wslot * 8]);
      gload_lds16(W2e + (size_t)(d0 + row) * (D_FF * 2) + (size_t)k0 * 2 + c * 16,
                  &Bs[wslot * 8]);
    }
    __syncthreads();
#pragma unroll
    for (int ks = 0; ks < 2; ks++) {
      frag_ab a[4], b[4];
#pragma unroll
      for (int mf = 0; mf < 4; mf++) {
        int row = wm*64 + mf*16 + lm;
        int c = (ks*4 + q) ^ (row & 7);
        a[mf] = *(const frag_ab*)(&As[row * 64 + c * 8]);
      }
#pragma unroll
      for (int nf = 0; nf < 4; nf++) {
        int row = wn*64 + nf*16 + lm;
        int c = (ks*4 + q) ^ (row & 7);
        b[nf] = *(const frag_ab*)(&Bs[row * 64 + c * 8]);
      }
#pragma unroll
      for (int mf = 0; mf < 4; mf++)
#pragma unroll
        for (int nf = 0; nf < 4; nf++)
          acc[mf][nf] = __builtin_amdgcn_mfma_f32_16x16x32_bf16(a[mf], b[nf], acc[mf][nf], 0, 0, 0);
    }
    __syncthreads();
  }
#pragma unroll
  for (int mf = 0; mf < 4; mf++) {
#pragma unroll
    for (int r = 0; r < 4; r++) {
      int row = wm*64 + mf*16 + q*4 + r;
      if (row < mrows) {
        float w = pw[base + row];
        float* orow = eo + (size_t)(base + row) * D_MODEL;
#pragma unroll
        for (int nf = 0; nf < 4; nf++)
          orow[d0 + wn*64 + nf*16 + lm] = w * acc[mf][nf][r];
      }
    }
  }
}

// ======================= FALLBACK PATH (original kernels) ===========================
__global__ __launch_bounds__(256) void k_gemm1(
    const float* __restrict__ x, const float* __restrict__ W1,
    const float* __restrict__ W3,
    const int* __restrict__ perm, const int* __restrict__ off,
    const int* __restrict__ tile_e, const int* __restrict__ tile_m,
    const int* __restrict__ cnt, bf16* __restrict__ H) {
  const int e = tile_e[blockIdx.y];
  if (e < 0) return;
  const int ms = tile_m[blockIdx.y];
  int mrows = cnt[e] - ms; if (mrows > 128) mrows = 128;
  const int f0 = blockIdx.x * 128;
  const int base = off[e] + ms;

  __shared__ __align__(16) bf16 As [128 * 40];
  __shared__ __align__(16) bf16 B1s[128 * 40];
  __shared__ __align__(16) bf16 B3s[128 * 40];
  __shared__ int permS[128];

  const int t = threadIdx.x;
  const int lane = t & 63, wid = t >> 6;
  const int wm = wid & 1, wn = wid >> 1;
  const int lm = lane & 15, q = lane >> 4;

  if (t < 128) permS[t] = (t < mrows) ? perm[base + t] : 0;

  frag_cd accg[4][4], accu[4][4];
#pragma unroll
  for (int i = 0; i < 4; i++)
#pragma unroll
    for (int j = 0; j < 4; j++) {
      accg[i][j] = {0.f,0.f,0.f,0.f};
      accu[i][j] = {0.f,0.f,0.f,0.f};
    }

  const float* W1e = W1 + (size_t)e * D_MODEL * D_FF;
  const float* W3e = W3 + (size_t)e * D_MODEL * D_FF;
  __syncthreads();

  for (int k0 = 0; k0 < D_MODEL; k0 += 32) {
#pragma unroll
    for (int i = 0; i < 4; i++) {
      int s = t + i * 256;
      int row = s >> 3, kg = s & 7;
      float4 v = make_float4(0.f, 0.f, 0.f, 0.f);
      if (row < mrows) {
        int tok = permS[row];
        v = *(const float4*)(x + (size_t)tok * D_MODEL + k0 + kg * 4);
      }
      *(short4*)(&As[row * 40 + kg * 4]) = f2bf4(v);
    }
#pragma unroll
    for (int i = 0; i < 2; i++) {
      int s = t + i * 256;
      int f = s & 127, kg = s >> 7;
      const float* g1 = W1e + (size_t)(k0 + kg * 8) * D_FF + f0 + f;
      const float* g3 = W3e + (size_t)(k0 + kg * 8) * D_FF + f0 + f;
      short r1[8], r3[8];
#pragma unroll
      for (int j = 0; j < 8; j++) r1[j] = f2bf_s(g1[(size_t)j * D_FF]);
#pragma unroll
      for (int j = 0; j < 8; j++) r3[j] = f2bf_s(g3[(size_t)j * D_FF]);
      *(frag_ab*)(&B1s[f * 40 + kg * 8]) = *(const frag_ab*)r1;
      *(frag_ab*)(&B3s[f * 40 + kg * 8]) = *(const frag_ab*)r3;
    }
    __syncthreads();
    frag_ab a[4], b1[4], b3[4];
#pragma unroll
    for (int mf = 0; mf < 4; mf++)
      a[mf] = *(const frag_ab*)(&As[(wm*64 + mf*16 + lm) * 40 + q*8]);
#pragma unroll
    for (int nf = 0; nf < 4; nf++) {
      b1[nf] = *(const frag_ab*)(&B1s[(wn*64 + nf*16 + lm) * 40 + q*8]);
      b3[nf] = *(const frag_ab*)(&B3s[(wn*64 + nf*16 + lm) * 40 + q*8]);
    }
#pragma unroll
    for (int mf = 0; mf < 4; mf++)
#pragma unroll
      for (int nf = 0; nf < 4; nf++) {
        accg[mf][nf] = __builtin_amdgcn_mfma_f32_16x16x32_bf16(a[mf], b1[nf], accg[mf][nf], 0, 0, 0);
        accu[mf][nf] = __builtin_amdgcn_mfma_f32_16x16x32_bf16(a[mf], b3[nf], accu[mf][nf], 0, 0, 0);
      }
    __syncthreads();
  }
#pragma unroll
  for (int mf = 0; mf < 4; mf++) {
#pragma unroll
    for (int r = 0; r < 4; r++) {
      int row = wm*64 + mf*16 + q*4 + r;
      if (row < mrows) {
        bf16* hrow = H + (size_t)(base + row) * D_FF;
#pragma unroll
        for (int nf = 0; nf < 4; nf++) {
          float g = accg[mf][nf][r];
          float u = accu[mf][nf][r];
          float h = g * u / (1.f + expf(-g));
          hrow[f0 + wn*64 + nf*16 + lm] = __float2bfloat16(h);
        }
      }
    }
  }
}

__global__ __launch_bounds__(256) void k_gemm2(
    const bf16* __restrict__ H, const float* __restrict__ W2,
    const float* __restrict__ pw,
    const int* __restrict__ off, const int* __restrict__ tile_e,
    const int* __restrict__ tile_m, const int* __restrict__ cnt,
    float* __restrict__ eo) {
  const int e = tile_e[blockIdx.y];
  if (e < 0) return;
  const int ms = tile_m[blockIdx.y];
  int mrows = cnt[e] - ms; if (mrows > 128) mrows = 128;
  const int d0 = blockIdx.x * 128;
  const int base = off[e] + ms;

  __shared__ __align__(16) bf16 As[128 * 40];
  __shared__ __align__(16) bf16 Bs[128 * 40];

  const int t = threadIdx.x;
  const int lane = t & 63, wid = t >> 6;
  const int wm = wid & 1, wn = wid >> 1;
  const int lm = lane & 15, q = lane >> 4;

  frag_cd acc[4][4];
#pragma unroll
  for (int i = 0; i < 4; i++)
#pragma unroll
    for (int j = 0; j < 4; j++) acc[i][j] = {0.f,0.f,0.f,0.f};

  const float* W2e = W2 + (size_t)e * D_FF * D_MODEL;
  const short* Hs = (const short*)H;

  for (int k0 = 0; k0 < D_FF; k0 += 32) {
#pragma unroll
    for (int i = 0; i < 2; i++) {
      int s = t + i * 256;
      int row = s >> 2, kg = s & 3;
      frag_ab v = {0,0,0,0,0,0,0,0};
      if (row < mrows)
        v = *(const frag_ab*)(Hs + (size_t)(base + row) * D_FF + k0 + kg * 8);
      *(frag_ab*)(&As[row * 40 + kg * 8]) = v;
    }
#pragma unroll
    for (int i = 0; i < 2; i++) {
      int s = t + i * 256;
      int dd = s & 127, kg = s >> 7;
      const float* g2 = W2e + (size_t)(k0 + kg * 8) * D_MODEL + d0 + dd;
      short r2[8];
#pragma unroll
      for (int j = 0; j < 8; j++) r2[j] = f2bf_s(g2[(size_t)j * D_MODEL]);
      *(frag_ab*)(&Bs[dd * 40 + kg * 8]) = *(const frag_ab*)r2;
    }
    __syncthreads();
    frag_ab a[4], b[4];
#pragma unroll
    for (int mf = 0; mf < 4; mf++)
      a[mf] = *(const frag_ab*)(&As[(wm*64 + mf*16 + lm) * 40 + q*8]);
#pragma unroll
    for (int nf = 0; nf < 4; nf++)
      b[nf] = *(const frag_ab*)(&Bs[(wn*64 + nf*16 + lm) * 40 + q*8]);
#pragma unroll
    for (int mf = 0; mf < 4; mf++)
#pragma unroll
      for (int nf = 0; nf < 4; nf++)
        acc[mf][nf] = __builtin_amdgcn_mfma_f32_16x16x32_bf16(a[mf], b[nf], acc[mf][nf], 0, 0, 0);
    __syncthreads();
  }
#pragma unroll
  for (int mf = 0; mf < 4; mf++) {
#pragma unroll
    for (int r = 0; r < 4; r++) {
      int row = wm*64 + mf*16 + q*4 + r;
      if (row < mrows) {
        float w = pw[base + row];
        float* orow = eo + (size_t)(base + row) * D_MODEL;
#pragma unroll
        for (int nf = 0; nf < 4; nf++)
          orow[d0 + wn*64 + nf*16 + lm] = w * acc[mf][nf][r];
      }
    }
  }
}

// ---------------- K6: combine the two expert outputs per token ----------------------
__global__ void k_combine(const float* __restrict__ eo, const int* __restrict__ posof,
                          float* __restrict__ out) {
  int idx = blockIdx.x * 256 + threadIdx.x;
  int n = idx >> 9;
  int c = (idx & 511) * 4;
  int p0 = posof[n*2], p1 = posof[n*2+1];
  const float4 a = *(const float4*)(eo + (size_t)p0 * D_MODEL + c);
  const float4 b = *(const float4*)(eo + (size_t)p1 * D_MODEL + c);
  float4 r;
  r.x = a.x + b.x; r.y = a.y + b.y; r.z = a.z + b.z; r.w = a.w + b.w;
  *(float4*)(out + (size_t)n * D_MODEL + c) = r;
}

extern "C" void kernel_launch(void* const* d_in, const int* in_sizes, int n_in,
                              void* d_out, int out_size, void* d_ws, size_t ws_size,
                              hipStream_t stream) {
  const float* x  = (const float*)d_in[0];
  const float* Wr = (const float*)d_in[1];
  const float* W1 = (const float*)d_in[2];
  const float* W3 = (const float*)d_in[3];
  const float* W2 = (const float*)d_in[4];
  float* out = (float*)d_out;
  char* ws = (char*)d_ws;

  // fast path needs: W1b(128MiB)+W3b(128MiB)+H(32MiB)+ctrl; W2b/eo alias W1b/W3b
  // after gemm1. +1MiB slack covers gemm2's guarded-but-issued A reads past H end.
  const size_t REQ = (290ull << 20);
  if (ws_size >= REQ) {
    bf16*  W1b = (bf16*)(ws);
    bf16*  W3b = (bf16*)(ws + (128ull << 20));
    bf16*  Hb  = (bf16*)(ws + (256ull << 20));
    bf16*  W2b = (bf16*)(ws);                    // alias: W1b dead after gemm1
    float* eo  = (float*)(ws + (128ull << 20));  // alias: W3b dead after gemm1
    char*  ib  = ws + (289ull << 20);
    int*   perm  = (int*)(ib);
    float* pw    = (float*)(ib + 16384);
    int*   posof = (int*)(ib + 32768);
    int*   tki   = (int*)(ib + 49152);
    float* tkw   = (float*)(ib + 65536);
    int*   cnt   = (int*)(ib + 81920);
    int*   cur   = (int*)(ib + 82048);
    int*   off   = (int*)(ib + 82176);
    int*   te    = (int*)(ib + 82432);
    int*   tm    = (int*)(ib + 82688);
    float* psum  = (float*)(ib + 82944);

    k_zero<<<1, 64, 0, stream>>>(cnt, cur, psum);
    k_route<<<NTOK, 256, 0, stream>>>(x, Wr, tki, tkw, cnt, psum);
    k_scan<<<1, 1, 0, stream>>>(cnt, psum, off, te, tm, out + (size_t)NTOK * D_MODEL);
    k_assign<<<NTOK/256, 256, 0, stream>>>(tki, tkw, off, cur, perm, pw, posof);
    // W1 + W3 transpose/convert in one launch (z = expert | which<<3)
    k_tpose_dual<D_MODEL, D_FF><<<dim3(D_FF/64, D_MODEL/128, 16), 256, 0, stream>>>(
        W1, W3, W1b, W3b);
    k_gemm1n<<<dim3(D_FF/128, MAXTILES), 256, 0, stream>>>(x, W1b, W3b, perm, off, te, tm, cnt, Hb);
    k_tpose<D_FF, D_MODEL><<<dim3(D_MODEL/64, D_FF/128, NEXP), 256, 0, stream>>>(W2, W2b);
    k_gemm2n<<<dim3(D_MODEL/128, MAXTILES), 256, 0, stream>>>(Hb, W2b, pw, off, te, tm, cnt, eo);
    k_combine<<<(NTOK*(D_MODEL/4))/256, 256, 0, stream>>>(eo, posof, out);
  } else {
    // -------- fallback: original 67 MiB layout + original kernels --------
    bf16*  H    = (bf16*)(ws);
    float* eo   = (float*)(ws + 33554432);
    char*  ib   = ws + 67108864;
    int*   perm  = (int*)(ib);
    float* pw    = (float*)(ib + 16384);
    int*   posof = (int*)(ib + 32768);
    int*   tki   = (int*)(ib + 49152);
    float* tkw   = (float*)(ib + 65536);
    int*   cnt   = (int*)(ib + 81920);
    int*   cur   = (int*)(ib + 82048);
    int*   off   = (int*)(ib + 82176);
    int*   te    = (int*)(ib + 82432);
    int*   tm    = (int*)(ib + 82688);
    float* psum  = (float*)(ib + 82944);

    k_zero<<<1, 64, 0, stream>>>(cnt, cur, psum);
    k_route<<<NTOK, 256, 0, stream>>>(x, Wr, tki, tkw, cnt, psum);
    k_scan<<<1, 1, 0, stream>>>(cnt, psum, off, te, tm, out + (size_t)NTOK * D_MODEL);
    k_assign<<<NTOK/256, 256, 0, stream>>>(tki, tkw, off, cur, perm, pw, posof);
    k_gemm1<<<dim3(D_FF/128, MAXTILES), 256, 0, stream>>>(x, W1, W3, perm, off, te, tm, cnt, H);
    k_gemm2<<<dim3(D_MODEL/128, MAXTILES), 256, 0, stream>>>(H, W2, pw, off, te, tm, cnt, eo);
    k_combine<<<(NTOK*(D_MODEL/4))/256, 256, 0, stream>>>(eo, posof, out);
  }
}

// Round 4
// 1296.993 us; speedup vs baseline: 1.3633x; 1.0236x over previous
//
#include <hip/hip_runtime.h>
#include <hip/hip_bf16.h>
#include <math.h>

#define D_MODEL 2048
#define D_FF    4096
#define NTOK    2048
#define NEXP    8
#define NPAIR   (NTOK*2)      // 4096 (token, expert) pairs, always exactly 2 per token
#define MAXTILES 48           // sum_e ceil(cnt_e/128) <= 4096/128 + 8 = 40

typedef __hip_bfloat16 bf16;
using frag_ab = __attribute__((ext_vector_type(8))) short;  // 8 bf16 (4 VGPRs)
using frag_cd = __attribute__((ext_vector_type(4))) float;  // 4 fp32 acc

__device__ __forceinline__ short f2bf_s(float f) {
  __hip_bfloat16 h = __float2bfloat16(f);
  union { __hip_bfloat16 b; short s; } u; u.b = h; return u.s;
}
__device__ __forceinline__ short4 f2bf4(const float4 v) {
  short4 r; r.x = f2bf_s(v.x); r.y = f2bf_s(v.y); r.z = f2bf_s(v.z); r.w = f2bf_s(v.w);
  return r;
}
__device__ __forceinline__ frag_ab pack8(const float4 v0, const float4 v1) {
  frag_ab r;
  r[0] = f2bf_s(v0.x); r[1] = f2bf_s(v0.y); r[2] = f2bf_s(v0.z); r[3] = f2bf_s(v0.w);
  r[4] = f2bf_s(v1.x); r[5] = f2bf_s(v1.y); r[6] = f2bf_s(v1.z); r[7] = f2bf_s(v1.w);
  return r;
}
// async 16B global -> LDS (linear dest = wave-uniform base + lane*16; global src per-lane)
__device__ __forceinline__ void gload_lds16(const void* g, void* l) {
  __builtin_amdgcn_global_load_lds(
      (const __attribute__((address_space(1))) unsigned int*)g,
      (__attribute__((address_space(3))) unsigned int*)l, 16, 0, 0);
}

// ---------------- K0: zero control arrays (ws is poisoned 0xAA every launch) --------
__global__ void k_zero(int* cnt, int* cur, float* psum) {
  int t = threadIdx.x;
  if (t < NEXP) { cnt[t] = 0; cur[t] = 0; psum[t] = 0.f; }
}

// ---------------- K1: routing + x->bf16 conversion ---------------------------------
// Xb (optional): plain [n][k] bf16 copy of x, consumed by k_gemm1x via swizzled-source
// global_load_lds. Reduction: wave shuffle-xor butterfly (no LDS conflicts, no serial
// 256-iteration loop).
__global__ void k_route(const float* __restrict__ x, const float* __restrict__ Wr,
                        int* __restrict__ tki, float* __restrict__ tkw,
                        int* __restrict__ cnt, float* __restrict__ psum,
                        bf16* __restrict__ Xb) {
  const int n = blockIdx.x;
  const int t = threadIdx.x;
  const int lane = t & 63, wid = t >> 6;
  const float* xr = x + (size_t)n * D_MODEL;
  if (Xb) {
    const float4* p4 = (const float4*)xr;
    float4 v0 = p4[t];
    float4 v1 = p4[t + 256];
    char* xrow = (char*)Xb + (size_t)n * (D_MODEL * 2);
    *(short4*)(xrow + t * 8)        = f2bf4(v0);
    *(short4*)(xrow + 2048 + t * 8) = f2bf4(v1);
  }
  float acc[NEXP];
#pragma unroll
  for (int e = 0; e < NEXP; e++) acc[e] = 0.f;
  for (int d = t; d < D_MODEL; d += 256) {
    float xv = xr[d];
#pragma unroll
    for (int e = 0; e < NEXP; e++) acc[e] += xv * Wr[e * D_MODEL + d];
  }
  // wave butterfly reduce (64 lanes)
#pragma unroll
  for (int e = 0; e < NEXP; e++)
#pragma unroll
    for (int off = 32; off > 0; off >>= 1)
      acc[e] += __shfl_xor(acc[e], off, 64);
  __shared__ float wred[4][NEXP];
  if (lane == 0)
#pragma unroll
    for (int e = 0; e < NEXP; e++) wred[wid][e] = acc[e];
  __syncthreads();
  __shared__ float logit[NEXP];
  if (t < NEXP) logit[t] = wred[0][t] + wred[1][t] + wred[2][t] + wred[3][t];
  __syncthreads();
  if (t == 0) {
    float m = logit[0];
#pragma unroll
    for (int e = 1; e < NEXP; e++) m = fmaxf(m, logit[e]);
    float p[NEXP]; float s = 0.f;
#pragma unroll
    for (int e = 0; e < NEXP; e++) { p[e] = expf(logit[e] - m); s += p[e]; }
    float inv = 1.f / s;
#pragma unroll
    for (int e = 0; e < NEXP; e++) p[e] *= inv;
    int i0 = 0;
#pragma unroll
    for (int e = 1; e < NEXP; e++) if (p[e] > p[i0]) i0 = e;
    int i1 = (i0 == 0) ? 1 : 0;
#pragma unroll
    for (int e = 0; e < NEXP; e++) if (e != i0 && e != i1 && p[e] > p[i1]) i1 = e;
    float wsum = p[i0] + p[i1];
    tki[n*2]   = i0;          tki[n*2+1] = i1;
    tkw[n*2]   = p[i0]/wsum;  tkw[n*2+1] = p[i1]/wsum;
    atomicAdd(&cnt[i0], 1);   atomicAdd(&cnt[i1], 1);
#pragma unroll
    for (int e = 0; e < NEXP; e++) atomicAdd(&psum[e], p[e]);
  }
}

// ---------------- K2: prefix scan, tile map, aux loss -------------------------------
__global__ void k_scan(const int* __restrict__ cnt, const float* __restrict__ psum,
                       int* __restrict__ off, int* __restrict__ te, int* __restrict__ tm,
                       float* __restrict__ aux_out) {
  if (threadIdx.x != 0) return;
  int o = 0;
  for (int e = 0; e < NEXP; e++) { off[e] = o; o += cnt[e]; }
  off[NEXP] = o;
  int nt = 0;
  for (int e = 0; e < NEXP; e++)
    for (int msv = 0; msv < cnt[e]; msv += 128) { te[nt] = e; tm[nt] = msv; nt++; }
  for (; nt < MAXTILES; nt++) { te[nt] = -1; tm[nt] = 0; }
  float aux = 0.f;
  for (int e = 0; e < NEXP; e++)
    aux += ((float)cnt[e] / (float)NPAIR) * (psum[e] / (float)NTOK);
  aux_out[0] = aux * 0.01f * (float)NEXP;
}

// ---------------- K3: assign ranks, build gather lists ------------------------------
__global__ void k_assign(const int* __restrict__ tki, const float* __restrict__ tkw,
                         const int* __restrict__ off, int* __restrict__ cur,
                         int* __restrict__ perm, float* __restrict__ pw,
                         int* __restrict__ posof) {
  int n = blockIdx.x * blockDim.x + threadIdx.x;
  if (n >= NTOK) return;
#pragma unroll
  for (int k = 0; k < 2; k++) {
    int e = tki[n*2+k];
    int r = atomicAdd(&cur[e], 1);
    int pos = off[e] + r;
    perm[pos] = n;
    pw[pos]   = tkw[n*2+k];
    posof[n*2+k] = pos;
  }
}

// ======================= FAST PATH =======================
// K-T: transpose+convert fp32 [E][K][F] -> bf16 [E][F][K], pre-swizzled:
// within each 64-k group (128 B), physical 16B chunk c holds logical k-octet (c ^ (f&7)).
template<int K, int F>
__device__ __forceinline__ void tpose_body(const float* __restrict__ s,
                                           char* __restrict__ d,
                                           int k0, int f0, int t, float* T /*[128*64]*/) {
  // phase 1: load [128k][64f] fp32 tile, swizzled float4 LDS writes
#pragma unroll
  for (int i = 0; i < 8; i++) {
    int sl = t + i * 256;              // 2048 slots = 128 rows x 16 quads
    int kr = sl >> 4, q4 = sl & 15;
    float4 v = *(const float4*)(s + (size_t)(k0 + kr) * F + f0 + q4 * 4);
    int qs = q4 ^ ((kr >> 3) & 7);
    *(float4*)(&T[kr * 64 + qs * 4]) = v;
  }
  __syncthreads();
  // phase 2: emit [64f][128k] bf16, chunk c of group g holds octet l = c ^ (f&7)
#pragma unroll
  for (int i = 0; i < 4; i++) {
    int sl = t + i * 256;              // 1024 slots = 64 rows x 2 groups x 8 chunks
    int fr = sl >> 4, cg = sl & 15;
    int g = cg >> 3, c = cg & 7;
    int l = c ^ (fr & 7);
    int rbase = g * 64 + l * 8;        // (rbase>>3)&7 == l  (j<8 doesn't carry)
    int col = (fr & 3) + (((fr >> 2) ^ l) << 2);
    frag_ab r;
#pragma unroll
    for (int j = 0; j < 8; j++) r[j] = f2bf_s(T[(rbase + j) * 64 + col]);
    *(frag_ab*)(d + (size_t)(f0 + fr) * K * 2 + (size_t)k0 * 2 + g * 128 + c * 16) = r;
  }
}

template<int K, int F>
__global__ __launch_bounds__(256) void k_tpose(const float* __restrict__ src,
                                               bf16* __restrict__ dst) {
  __shared__ __align__(16) float T[128 * 64];
  const int e = blockIdx.z;
  tpose_body<K, F>(src + (size_t)e * K * F, (char*)(dst + (size_t)e * F * K),
                   blockIdx.y * 128, blockIdx.x * 64, threadIdx.x, T);
}

template<int K, int F>
__global__ __launch_bounds__(256) void k_tpose_dual(const float* __restrict__ srcA,
                                                    const float* __restrict__ srcB,
                                                    bf16* __restrict__ dstA,
                                                    bf16* __restrict__ dstB) {
  __shared__ __align__(16) float T[128 * 64];
  const int e = blockIdx.z & 7;
  const float* src = (blockIdx.z & 8) ? srcB : srcA;
  bf16*        dst = (blockIdx.z & 8) ? dstB : dstA;
  tpose_body<K, F>(src + (size_t)e * K * F, (char*)(dst + (size_t)e * F * K),
                   blockIdx.y * 128, blockIdx.x * 64, threadIdx.x, T);
}

// K4x (tier-1): fused GEMM1, ALL-async staging. A from Xb (plain bf16 rows) via
// per-lane-source global_load_lds: gather (perm) and XOR-swizzle are folded into the
// global source address; LDS dest is linear. B1/B3 from pre-swizzled weights.
// K-loop body: 12 gload_lds + 24 ds_read_b128 + 32 MFMA (pure m97 shape).
__global__ __launch_bounds__(256, 2) void k_gemm1x(
    const bf16* __restrict__ Xb, const bf16* __restrict__ W1b,
    const bf16* __restrict__ W3b,
    const int* __restrict__ perm, const int* __restrict__ off,
    const int* __restrict__ tile_e, const int* __restrict__ tile_m,
    const int* __restrict__ cnt, bf16* __restrict__ H) {
  const int e = tile_e[blockIdx.y];
  if (e < 0) return;
  const int ms = tile_m[blockIdx.y];
  int mrows = cnt[e] - ms; if (mrows > 128) mrows = 128;
  const int f0 = blockIdx.x * 128;
  const int base = off[e] + ms;

  __shared__ __align__(16) bf16 As [128 * 64];
  __shared__ __align__(16) bf16 B1s[128 * 64];
  __shared__ __align__(16) bf16 B3s[128 * 64];
  __shared__ int permS[128];

  const int t = threadIdx.x;
  const int lane = t & 63;
  const int wuni = t & 192;          // wave-uniform base (4 waves)
  const int wid = t >> 6;
  const int wm = wid & 1, wn = wid >> 1;
  const int lm = lane & 15, q = lane >> 4;

  if (t < 128) permS[t] = (t < mrows) ? perm[base + t] : 0;

  frag_cd accg[4][4], accu[4][4];
#pragma unroll
  for (int i = 0; i < 4; i++)
#pragma unroll
    for (int j = 0; j < 4; j++) {
      accg[i][j] = {0.f,0.f,0.f,0.f};
      accu[i][j] = {0.f,0.f,0.f,0.f};
    }

  const char* W1e = (const char*)(W1b + (size_t)e * D_MODEL * D_FF);  // [f][k] bf16
  const char* W3e = (const char*)(W3b + (size_t)e * D_MODEL * D_FF);
  const char* Xc  = (const char*)Xb;
  __syncthreads();

  // per-thread A source offsets (row/c fixed per (i,t); swizzle folded into source)
  size_t aoff[4];
#pragma unroll
  for (int i = 0; i < 4; i++) {
    int slot = i * 256 + t;
    int row = slot >> 3, c = slot & 7;
    aoff[i] = (size_t)permS[row] * (D_MODEL * 2) + (size_t)((c ^ (row & 7)) * 16);
  }

  for (int k0 = 0; k0 < D_MODEL; k0 += 64) {
    const size_t kb = (size_t)k0 * 2;
#pragma unroll
    for (int i = 0; i < 4; i++) {
      int wslot = i * 256 + wuni;
      int slot  = wslot + lane;
      int row = slot >> 3, c = slot & 7;
      size_t gb = (size_t)(f0 + row) * (D_MODEL * 2) + kb + c * 16;
      gload_lds16(W1e + gb, &B1s[wslot * 8]);
      gload_lds16(W3e + gb, &B3s[wslot * 8]);
      gload_lds16(Xc + aoff[i] + kb, &As[wslot * 8]);
    }
    __syncthreads();
#pragma unroll
    for (int ks = 0; ks < 2; ks++) {
      frag_ab a[4], b1[4], b3[4];
#pragma unroll
      for (int mf = 0; mf < 4; mf++) {
        int row = wm*64 + mf*16 + lm;
        int c = (ks*4 + q) ^ (row & 7);
        a[mf] = *(const frag_ab*)(&As[row * 64 + c * 8]);
      }
#pragma unroll
      for (int nf = 0; nf < 4; nf++) {
        int row = wn*64 + nf*16 + lm;
        int c = (ks*4 + q) ^ (row & 7);
        b1[nf] = *(const frag_ab*)(&B1s[row * 64 + c * 8]);
        b3[nf] = *(const frag_ab*)(&B3s[row * 64 + c * 8]);
      }
#pragma unroll
      for (int mf = 0; mf < 4; mf++)
#pragma unroll
        for (int nf = 0; nf < 4; nf++) {
          accg[mf][nf] = __builtin_amdgcn_mfma_f32_16x16x32_bf16(a[mf], b1[nf], accg[mf][nf], 0, 0, 0);
          accu[mf][nf] = __builtin_amdgcn_mfma_f32_16x16x32_bf16(a[mf], b3[nf], accu[mf][nf], 0, 0, 0);
        }
    }
    __syncthreads();
  }
  // epilogue: H = silu(g)*u, stored PRE-SWIZZLED bf16 for gemm2's global_load_lds.
#pragma unroll
  for (int mf = 0; mf < 4; mf++) {
#pragma unroll
    for (int r = 0; r < 4; r++) {
      int row = wm*64 + mf*16 + q*4 + r;
      if (row < mrows) {
        char* hrow = (char*)H + (size_t)(base + row) * (D_FF * 2);
        int key = row & 7;
#pragma unroll
        for (int nf = 0; nf < 4; nf++) {
          float g = accg[mf][nf][r];
          float u = accu[mf][nf][r];
          float h = g * u / (1.f + expf(-g));   // silu(g)*u
          int f = f0 + wn*64 + nf*16 + lm;
          int grp = f >> 6, oct = (f >> 3) & 7, j = f & 7;
          *(bf16*)(hrow + grp*128 + ((oct ^ key) * 16) + j*2) = __float2bfloat16(h);
        }
      }
    }
  }
}

// K4g (tier-2, = R1): fused GEMM1 with in-kernel fp32 A gather+convert.
__global__ __launch_bounds__(256, 2) void k_gemm1g(
    const float* __restrict__ x, const bf16* __restrict__ W1b,
    const bf16* __restrict__ W3b,
    const int* __restrict__ perm, const int* __restrict__ off,
    const int* __restrict__ tile_e, const int* __restrict__ tile_m,
    const int* __restrict__ cnt, bf16* __restrict__ H) {
  const int e = tile_e[blockIdx.y];
  if (e < 0) return;
  const int ms = tile_m[blockIdx.y];
  int mrows = cnt[e] - ms; if (mrows > 128) mrows = 128;
  const int f0 = blockIdx.x * 128;
  const int base = off[e] + ms;

  __shared__ __align__(16) bf16 As [128 * 64];
  __shared__ __align__(16) bf16 B1s[128 * 64];
  __shared__ __align__(16) bf16 B3s[128 * 64];
  __shared__ int permS[128];

  const int t = threadIdx.x;
  const int lane = t & 63;
  const int wuni = t & 192;
  const int wid = t >> 6;
  const int wm = wid & 1, wn = wid >> 1;
  const int lm = lane & 15, q = lane >> 4;

  if (t < 128) permS[t] = (t < mrows) ? perm[base + t] : 0;

  frag_cd accg[4][4], accu[4][4];
#pragma unroll
  for (int i = 0; i < 4; i++)
#pragma unroll
    for (int j = 0; j < 4; j++) {
      accg[i][j] = {0.f,0.f,0.f,0.f};
      accu[i][j] = {0.f,0.f,0.f,0.f};
    }

  const char* W1e = (const char*)(W1b + (size_t)e * D_MODEL * D_FF);
  const char* W3e = (const char*)(W3b + (size_t)e * D_MODEL * D_FF);
  __syncthreads();

  for (int k0 = 0; k0 < D_MODEL; k0 += 64) {
#pragma unroll
    for (int i = 0; i < 4; i++) {
      int wslot = i * 256 + wuni;
      int slot  = wslot + lane;
      int row = slot >> 3, c = slot & 7;
      size_t gb = (size_t)(f0 + row) * (D_MODEL * 2) + (size_t)k0 * 2 + c * 16;
      gload_lds16(W1e + gb, &B1s[wslot * 8]);
      gload_lds16(W3e + gb, &B3s[wslot * 8]);
    }
#pragma unroll
    for (int i = 0; i < 4; i++) {
      int slot = i * 256 + t;
      int row = slot >> 3, c = slot & 7;
      int tok = permS[row];
      const float4* p = (const float4*)(x + (size_t)tok * D_MODEL + k0 + c * 8);
      frag_ab v = pack8(p[0], p[1]);
      *(frag_ab*)(&As[row * 64 + ((c ^ (row & 7)) * 8)]) = v;
    }
    __syncthreads();
#pragma unroll
    for (int ks = 0; ks < 2; ks++) {
      frag_ab a[4], b1[4], b3[4];
#pragma unroll
      for (int mf = 0; mf < 4; mf++) {
        int row = wm*64 + mf*16 + lm;
        int c = (ks*4 + q) ^ (row & 7);
        a[mf] = *(const frag_ab*)(&As[row * 64 + c * 8]);
      }
#pragma unroll
      for (int nf = 0; nf < 4; nf++) {
        int row = wn*64 + nf*16 + lm;
        int c = (ks*4 + q) ^ (row & 7);
        b1[nf] = *(const frag_ab*)(&B1s[row * 64 + c * 8]);
        b3[nf] = *(const frag_ab*)(&B3s[row * 64 + c * 8]);
      }
#pragma unroll
      for (int mf = 0; mf < 4; mf++)
#pragma unroll
        for (int nf = 0; nf < 4; nf++) {
          accg[mf][nf] = __builtin_amdgcn_mfma_f32_16x16x32_bf16(a[mf], b1[nf], accg[mf][nf], 0, 0, 0);
          accu[mf][nf] = __builtin_amdgcn_mfma_f32_16x16x32_bf16(a[mf], b3[nf], accu[mf][nf], 0, 0, 0);
        }
    }
    __syncthreads();
  }
#pragma unroll
  for (int mf = 0; mf < 4; mf++) {
#pragma unroll
    for (int r = 0; r < 4; r++) {
      int row = wm*64 + mf*16 + q*4 + r;
      if (row < mrows) {
        char* hrow = (char*)H + (size_t)(base + row) * (D_FF * 2);
        int key = row & 7;
#pragma unroll
        for (int nf = 0; nf < 4; nf++) {
          float g = accg[mf][nf][r];
          float u = accu[mf][nf][r];
          float h = g * u / (1.f + expf(-g));
          int f = f0 + wn*64 + nf*16 + lm;
          int grp = f >> 6, oct = (f >> 3) & 7, j = f & 7;
          *(bf16*)(hrow + grp*128 + ((oct ^ key) * 16) + j*2) = __float2bfloat16(h);
        }
      }
    }
  }
}

// K5n: GEMM2: eo = w * (H W2), 128x128 tile, BK=64, both operands via global_load_lds.
__global__ __launch_bounds__(256, 3) void k_gemm2n(
    const bf16* __restrict__ H, const bf16* __restrict__ W2b,
    const float* __restrict__ pw,
    const int* __restrict__ off, const int* __restrict__ tile_e,
    const int* __restrict__ tile_m, const int* __restrict__ cnt,
    float* __restrict__ eo) {
  const int e = tile_e[blockIdx.y];
  if (e < 0) return;
  const int ms = tile_m[blockIdx.y];
  int mrows = cnt[e] - ms; if (mrows > 128) mrows = 128;
  const int d0 = blockIdx.x * 128;
  const int base = off[e] + ms;

  __shared__ __align__(16) bf16 As[128 * 64];
  __shared__ __align__(16) bf16 Bs[128 * 64];

  const int t = threadIdx.x;
  const int lane = t & 63;
  const int wuni = t & 192;
  const int wid = t >> 6;
  const int wm = wid & 1, wn = wid >> 1;
  const int lm = lane & 15, q = lane >> 4;

  frag_cd acc[4][4];
#pragma unroll
  for (int i = 0; i < 4; i++)
#pragma unroll
    for (int j = 0; j < 4; j++) acc[i][j] = {0.f,0.f,0.f,0.f};

  const char* W2e = (const char*)(W2b + (size_t)e * D_FF * D_MODEL);  // [d][f] bf16
  const char* Hb  = (const char*)H;

  for (int k0 = 0; k0 < D_FF; k0 += 64) {
#pragma unroll
    for (int i = 0; i < 4; i++) {
      int wslot = i * 256 + wuni;
      int slot  = wslot + lane;
      int row = slot >> 3, c = slot & 7;
      gload_lds16(Hb + (size_t)(base + row) * (D_FF * 2) + (size_t)k0 * 2 + c * 16,
                  &As[wslot * 8]);
      gload_lds16(W2e + (size_t)(d0 + row) * (D_FF * 2) + (size_t)k0 * 2 + c * 16,
                  &Bs[wslot * 8]);
    }
    __syncthreads();
#pragma unroll
    for (int ks = 0; ks < 2; ks++) {
      frag_ab a[4], b[4];
#pragma unroll
      for (int mf = 0; mf < 4; mf++) {
        int row = wm*64 + mf*16 + lm;
        int c = (ks*4 + q) ^ (row & 7);
        a[mf] = *(const frag_ab*)(&As[row * 64 + c * 8]);
      }
#pragma unroll
      for (int nf = 0; nf < 4; nf++) {
        int row = wn*64 + nf*16 + lm;
        int c = (ks*4 + q) ^ (row & 7);
        b[nf] = *(const frag_ab*)(&Bs[row * 64 + c * 8]);
      }
#pragma unroll
      for (int mf = 0; mf < 4; mf++)
#pragma unroll
        for (int nf = 0; nf < 4; nf++)
          acc[mf][nf] = __builtin_amdgcn_mfma_f32_16x16x32_bf16(a[mf], b[nf], acc[mf][nf], 0, 0, 0);
    }
    __syncthreads();
  }
#pragma unroll
  for (int mf = 0; mf < 4; mf++) {
#pragma unroll
    for (int r = 0; r < 4; r++) {
      int row = wm*64 + mf*16 + q*4 + r;
      if (row < mrows) {
        float w = pw[base + row];
        float* orow = eo + (size_t)(base + row) * D_MODEL;
#pragma unroll
        for (int nf = 0; nf < 4; nf++)
          orow[d0 + wn*64 + nf*16 + lm] = w * acc[mf][nf][r];
      }
    }
  }
}

// ======================= FALLBACK PATH (original kernels, <290 MiB) =================
__global__ __launch_bounds__(256) void k_gemm1(
    const float* __restrict__ x, const float* __restrict__ W1,
    const float* __restrict__ W3,
    const int* __restrict__ perm, const int* __restrict__ off,
    const int* __restrict__ tile_e, const int* __restrict__ tile_m,
    const int* __restrict__ cnt, bf16* __restrict__ H) {
  const int e = tile_e[blockIdx.y];
  if (e < 0) return;
  const int ms = tile_m[blockIdx.y];
  int mrows = cnt[e] - ms; if (mrows > 128) mrows = 128;
  const int f0 = blockIdx.x * 128;
  const int base = off[e] + ms;

  __shared__ __align__(16) bf16 As [128 * 40];
  __shared__ __align__(16) bf16 B1s[128 * 40];
  __shared__ __align__(16) bf16 B3s[128 * 40];
  __shared__ int permS[128];

  const int t = threadIdx.x;
  const int lane = t & 63, wid = t >> 6;
  const int wm = wid & 1, wn = wid >> 1;
  const int lm = lane & 15, q = lane >> 4;

  if (t < 128) permS[t] = (t < mrows) ? perm[base + t] : 0;

  frag_cd accg[4][4], accu[4][4];
#pragma unroll
  for (int i = 0; i < 4; i++)
#pragma unroll
    for (int j = 0; j < 4; j++) {
      accg[i][j] = {0.f,0.f,0.f,0.f};
      accu[i][j] = {0.f,0.f,0.f,0.f};
    }

  const float* W1e = W1 + (size_t)e * D_MODEL * D_FF;
  const float* W3e = W3 + (size_t)e * D_MODEL * D_FF;
  __syncthreads();

  for (int k0 = 0; k0 < D_MODEL; k0 += 32) {
#pragma unroll
    for (int i = 0; i < 4; i++) {
      int s = t + i * 256;
      int row = s >> 3, kg = s & 7;
      float4 v = make_float4(0.f, 0.f, 0.f, 0.f);
      if (row < mrows) {
        int tok = permS[row];
        v = *(const float4*)(x + (size_t)tok * D_MODEL + k0 + kg * 4);
      }
      *(short4*)(&As[row * 40 + kg * 4]) = f2bf4(v);
    }
#pragma unroll
    for (int i = 0; i < 2; i++) {
      int s = t + i * 256;
      int f = s & 127, kg = s >> 7;
      const float* g1 = W1e + (size_t)(k0 + kg * 8) * D_FF + f0 + f;
      const float* g3 = W3e + (size_t)(k0 + kg * 8) * D_FF + f0 + f;
      short r1[8], r3[8];
#pragma unroll
      for (int j = 0; j < 8; j++) r1[j] = f2bf_s(g1[(size_t)j * D_FF]);
#pragma unroll
      for (int j = 0; j < 8; j++) r3[j] = f2bf_s(g3[(size_t)j * D_FF]);
      *(frag_ab*)(&B1s[f * 40 + kg * 8]) = *(const frag_ab*)r1;
      *(frag_ab*)(&B3s[f * 40 + kg * 8]) = *(const frag_ab*)r3;
    }
    __syncthreads();
    frag_ab a[4], b1[4], b3[4];
#pragma unroll
    for (int mf = 0; mf < 4; mf++)
      a[mf] = *(const frag_ab*)(&As[(wm*64 + mf*16 + lm) * 40 + q*8]);
#pragma unroll
    for (int nf = 0; nf < 4; nf++) {
      b1[nf] = *(const frag_ab*)(&B1s[(wn*64 + nf*16 + lm) * 40 + q*8]);
      b3[nf] = *(const frag_ab*)(&B3s[(wn*64 + nf*16 + lm) * 40 + q*8]);
    }
#pragma unroll
    for (int mf = 0; mf < 4; mf++)
#pragma unroll
      for (int nf = 0; nf < 4; nf++) {
        accg[mf][nf] = __builtin_amdgcn_mfma_f32_16x16x32_bf16(a[mf], b1[nf], accg[mf][nf], 0, 0, 0);
        accu[mf][nf] = __builtin_amdgcn_mfma_f32_16x16x32_bf16(a[mf], b3[nf], accu[mf][nf], 0, 0, 0);
      }
    __syncthreads();
  }
#pragma unroll
  for (int mf = 0; mf < 4; mf++) {
#pragma unroll
    for (int r = 0; r < 4; r++) {
      int row = wm*64 + mf*16 + q*4 + r;
      if (row < mrows) {
        bf16* hrow = H + (size_t)(base + row) * D_FF;
#pragma unroll
        for (int nf = 0; nf < 4; nf++) {
          float g = accg[mf][nf][r];
          float u = accu[mf][nf][r];
          float h = g * u / (1.f + expf(-g));
          hrow[f0 + wn*64 + nf*16 + lm] = __float2bfloat16(h);
        }
      }
    }
  }
}

__global__ __launch_bounds__(256) void k_gemm2(
    const bf16* __restrict__ H, const float* __restrict__ W2,
    const float* __restrict__ pw,
    const int* __restrict__ off, const int* __restrict__ tile_e,
    const int* __restrict__ tile_m, const int* __restrict__ cnt,
    float* __restrict__ eo) {
  const int e = tile_e[blockIdx.y];
  if (e < 0) return;
  const int ms = tile_m[blockIdx.y];
  int mrows = cnt[e] - ms; if (mrows > 128) mrows = 128;
  const int d0 = blockIdx.x * 128;
  const int base = off[e] + ms;

  __shared__ __align__(16) bf16 As[128 * 40];
  __shared__ __align__(16) bf16 Bs[128 * 40];

  const int t = threadIdx.x;
  const int lane = t & 63, wid = t >> 6;
  const int wm = wid & 1, wn = wid >> 1;
  const int lm = lane & 15, q = lane >> 4;

  frag_cd acc[4][4];
#pragma unroll
  for (int i = 0; i < 4; i++)
#pragma unroll
    for (int j = 0; j < 4; j++) acc[i][j] = {0.f,0.f,0.f,0.f};

  const float* W2e = W2 + (size_t)e * D_FF * D_MODEL;
  const short* Hs = (const short*)H;

  for (int k0 = 0; k0 < D_FF; k0 += 32) {
#pragma unroll
    for (int i = 0; i < 2; i++) {
      int s = t + i * 256;
      int row = s >> 2, kg = s & 3;
      frag_ab v = {0,0,0,0,0,0,0,0};
      if (row < mrows)
        v = *(const frag_ab*)(Hs + (size_t)(base + row) * D_FF + k0 + kg * 8);
      *(frag_ab*)(&As[row * 40 + kg * 8]) = v;
    }
#pragma unroll
    for (int i = 0; i < 2; i++) {
      int s = t + i * 256;
      int dd = s & 127, kg = s >> 7;
      const float* g2 = W2e + (size_t)(k0 + kg * 8) * D_MODEL + d0 + dd;
      short r2[8];
#pragma unroll
      for (int j = 0; j < 8; j++) r2[j] = f2bf_s(g2[(size_t)j * D_MODEL]);
      *(frag_ab*)(&Bs[dd * 40 + kg * 8]) = *(const frag_ab*)r2;
    }
    __syncthreads();
    frag_ab a[4], b[4];
#pragma unroll
    for (int mf = 0; mf < 4; mf++)
      a[mf] = *(const frag_ab*)(&As[(wm*64 + mf*16 + lm) * 40 + q*8]);
#pragma unroll
    for (int nf = 0; nf < 4; nf++)
      b[nf] = *(const frag_ab*)(&Bs[(wn*64 + nf*16 + lm) * 40 + q*8]);
#pragma unroll
    for (int mf = 0; mf < 4; mf++)
#pragma unroll
      for (int nf = 0; nf < 4; nf++)
        acc[mf][nf] = __builtin_amdgcn_mfma_f32_16x16x32_bf16(a[mf], b[nf], acc[mf][nf], 0, 0, 0);
    __syncthreads();
  }
#pragma unroll
  for (int mf = 0; mf < 4; mf++) {
#pragma unroll
    for (int r = 0; r < 4; r++) {
      int row = wm*64 + mf*16 + q*4 + r;
      if (row < mrows) {
        float w = pw[base + row];
        float* orow = eo + (size_t)(base + row) * D_MODEL;
#pragma unroll
        for (int nf = 0; nf < 4; nf++)
          orow[d0 + wn*64 + nf*16 + lm] = w * acc[mf][nf][r];
      }
    }
  }
}

// ---------------- K6: combine the two expert outputs per token ----------------------
__global__ void k_combine(const float* __restrict__ eo, const int* __restrict__ posof,
                          float* __restrict__ out) {
  int idx = blockIdx.x * 256 + threadIdx.x;
  int n = idx >> 9;
  int c = (idx & 511) * 4;
  int p0 = posof[n*2], p1 = posof[n*2+1];
  const float4 a = *(const float4*)(eo + (size_t)p0 * D_MODEL + c);
  const float4 b = *(const float4*)(eo + (size_t)p1 * D_MODEL + c);
  float4 r;
  r.x = a.x + b.x; r.y = a.y + b.y; r.z = a.z + b.z; r.w = a.w + b.w;
  *(float4*)(out + (size_t)n * D_MODEL + c) = r;
}

extern "C" void kernel_launch(void* const* d_in, const int* in_sizes, int n_in,
                              void* d_out, int out_size, void* d_ws, size_t ws_size,
                              hipStream_t stream) {
  const float* x  = (const float*)d_in[0];
  const float* Wr = (const float*)d_in[1];
  const float* W1 = (const float*)d_in[2];
  const float* W3 = (const float*)d_in[3];
  const float* W2 = (const float*)d_in[4];
  float* out = (float*)d_out;
  char* ws = (char*)d_ws;

  const size_t REQ1 = (304ull << 20);  // + Xb (8 MiB at [288,296))
  const size_t REQ2 = (290ull << 20);  // R1 layout
  if (ws_size >= REQ2) {
    const bool tier1 = (ws_size >= REQ1);
    bf16*  W1b = (bf16*)(ws);
    bf16*  W3b = (bf16*)(ws + (128ull << 20));
    bf16*  Hb  = (bf16*)(ws + (256ull << 20));
    bf16*  W2b = (bf16*)(ws);                    // alias: W1b dead after gemm1
    float* eo  = (float*)(ws + (128ull << 20));  // alias: W3b dead after gemm1
    bf16*  Xb  = tier1 ? (bf16*)(ws + (288ull << 20)) : nullptr;
    char*  ib  = ws + (tier1 ? (296ull << 20) : (289ull << 20));
    int*   perm  = (int*)(ib);
    float* pw    = (float*)(ib + 16384);
    int*   posof = (int*)(ib + 32768);
    int*   tki   = (int*)(ib + 49152);
    float* tkw   = (float*)(ib + 65536);
    int*   cnt   = (int*)(ib + 81920);
    int*   cur   = (int*)(ib + 82048);
    int*   off   = (int*)(ib + 82176);
    int*   te    = (int*)(ib + 82432);
    int*   tm    = (int*)(ib + 82688);
    float* psum  = (float*)(ib + 82944);

    k_zero<<<1, 64, 0, stream>>>(cnt, cur, psum);
    k_route<<<NTOK, 256, 0, stream>>>(x, Wr, tki, tkw, cnt, psum, Xb);
    k_scan<<<1, 1, 0, stream>>>(cnt, psum, off, te, tm, out + (size_t)NTOK * D_MODEL);
    k_assign<<<NTOK/256, 256, 0, stream>>>(tki, tkw, off, cur, perm, pw, posof);
    k_tpose_dual<D_MODEL, D_FF><<<dim3(D_FF/64, D_MODEL/128, 16), 256, 0, stream>>>(
        W1, W3, W1b, W3b);
    if (tier1)
      k_gemm1x<<<dim3(D_FF/128, MAXTILES), 256, 0, stream>>>(Xb, W1b, W3b, perm, off, te, tm, cnt, Hb);
    else
      k_gemm1g<<<dim3(D_FF/128, MAXTILES), 256, 0, stream>>>(x, W1b, W3b, perm, off, te, tm, cnt, Hb);
    k_tpose<D_FF, D_MODEL><<<dim3(D_MODEL/64, D_FF/128, NEXP), 256, 0, stream>>>(W2, W2b);
    k_gemm2n<<<dim3(D_MODEL/128, MAXTILES), 256, 0, stream>>>(Hb, W2b, pw, off, te, tm, cnt, eo);
    k_combine<<<(NTOK*(D_MODEL/4))/256, 256, 0, stream>>>(eo, posof, out);
  } else {
    // -------- fallback: original 67 MiB layout + original kernels --------
    bf16*  H    = (bf16*)(ws);
    float* eo   = (float*)(ws + 33554432);
    char*  ib   = ws + 67108864;
    int*   perm  = (int*)(ib);
    float* pw    = (float*)(ib + 16384);
    int*   posof = (int*)(ib + 32768);
    int*   tki   = (int*)(ib + 49152);
    float* tkw   = (float*)(ib + 65536);
    int*   cnt   = (int*)(ib + 81920);
    int*   cur   = (int*)(ib + 82048);
    int*   off   = (int*)(ib + 82176);
    int*   te    = (int*)(ib + 82432);
    int*   tm    = (int*)(ib + 82688);
    float* psum  = (float*)(ib + 82944);

    k_zero<<<1, 64, 0, stream>>>(cnt, cur, psum);
    k_route<<<NTOK, 256, 0, stream>>>(x, Wr, tki, tkw, cnt, psum, nullptr);
    k_scan<<<1, 1, 0, stream>>>(cnt, psum, off, te, tm, out + (size_t)NTOK * D_MODEL);
    k_assign<<<NTOK/256, 256, 0, stream>>>(tki, tkw, off, cur, perm, pw, posof);
    k_gemm1<<<dim3(D_FF/128, MAXTILES), 256, 0, stream>>>(x, W1, W3, perm, off, te, tm, cnt, H);
    k_gemm2<<<dim3(D_MODEL/128, MAXTILES), 256, 0, stream>>>(H, W2, pw, off, te, tm, cnt, eo);
    k_combine<<<(NTOK*(D_MODEL/4))/256, 256, 0, stream>>>(eo, posof, out);
  }
}